// Round 1
// 409.218 us; speedup vs baseline: 1.0572x; 1.0572x over previous
//
#include <hip/hip_runtime.h>

typedef unsigned short u16;
typedef __attribute__((ext_vector_type(8))) short bf16x8;
typedef __attribute__((ext_vector_type(4))) float f32x4;

__device__ inline float bf2f(u16 u) {
    unsigned v = ((unsigned)u) << 16;
    return __builtin_bit_cast(float, v);
}
__device__ inline u16 f2bf(float f) {
    unsigned u = __builtin_bit_cast(unsigned, f);
    u += 0x7fff + ((u >> 16) & 1);   // RNE
    return (u16)(u >> 16);
}

// async global->LDS, 16B per lane. LDS dest = wave-uniform base + lane*16.
__device__ inline void gload_lds16(const void* g, void* l) {
    __builtin_amdgcn_global_load_lds(
        (const __attribute__((address_space(1))) unsigned int*)(unsigned long long)g,
        (__attribute__((address_space(3))) unsigned int*)(unsigned)(unsigned long long)l,
        16, 0, 0);
}

// ---------------------------------------------------------------- cast x -> bf16 (8 floats/thread, one 16B store)
__global__ __launch_bounds__(256) void cast_x(const float4* __restrict__ x,
                                              bf16x8* __restrict__ xb) {
    long i = (long)blockIdx.x * 256 + threadIdx.x;
    float4 v0 = x[2 * i];
    float4 v1 = x[2 * i + 1];
    bf16x8 o;
    o[0] = (short)f2bf(v0.x); o[1] = (short)f2bf(v0.y);
    o[2] = (short)f2bf(v0.z); o[3] = (short)f2bf(v0.w);
    o[4] = (short)f2bf(v1.x); o[5] = (short)f2bf(v1.y);
    o[6] = (short)f2bf(v1.z); o[7] = (short)f2bf(v1.w);
    xb[i] = o;
}

// ---------------------------------------------------------------- weight fold/transpose (f32 inputs)
__global__ __launch_bounds__(256) void fold_weights(
    const float* __restrict__ Wq, const float* __restrict__ Wk,
    const float* __restrict__ Wv, const float* __restrict__ Wo,
    const float* __restrict__ bq, const float* __restrict__ bk,
    const float* __restrict__ bv, const float* __restrict__ proj,
    u16* __restrict__ WallT, u16* __restrict__ WoT, float* __restrict__ bias_all)
{
    const int r = blockIdx.x;
    const int tid = threadIdx.x;
    if (r < 1024) {
        const float* W  = (r < 512) ? Wq : Wk;
        const float* bb = (r < 512) ? bq : bk;
        const int h = (r & 511) >> 5, f = r & 31;
        __shared__ float pcol[64];
        if (tid < 64) pcol[tid] = proj[tid * 32 + f];
        __syncthreads();
        for (int it = 0; it < 4; it++) {
            const int kin = it * 256 + tid;
            const float* wrow = W + (long)kin * 1024 + h * 64;
            float acc = 0.f;
            #pragma unroll
            for (int d = 0; d < 64; d += 4) {
                float4 w = *(const float4*)(wrow + d);
                acc += w.x * pcol[d] + w.y * pcol[d + 1] + w.z * pcol[d + 2] + w.w * pcol[d + 3];
            }
            WallT[(long)r * 1024 + kin] = f2bf(acc);
        }
        if (tid == 0) {
            float a = 0.f;
            for (int d = 0; d < 64; d++) a += bb[h * 64 + d] * pcol[d];
            bias_all[r] = a;
        }
    } else if (r < 2048) {
        const int c = r - 1024;
        for (int it = 0; it < 4; it++) {
            const int kin = it * 256 + tid;
            WallT[(long)r * 1024 + kin] = f2bf(Wv[(long)kin * 1024 + c]);
        }
        if (tid == 0) bias_all[r] = bv[c];
    } else {
        const int c = r - 2048;
        for (int it = 0; it < 4; it++) {
            const int kin = it * 256 + tid;
            WoT[(long)c * 1024 + kin] = f2bf(Wo[(long)kin * 1024 + c]);
        }
    }
}

// ---------------------------------------------------------------- 256x256 8-phase pipelined bf16 MFMA GEMM
// K=1024 fixed. B transposed [N][K]. 512 threads = 8 waves (2m x 4n), per-wave
// output 128x64 (8 m-frags x 4 n-frags of 16x16x32 MFMA).
// LDS 128KiB: [buf(2)][khalf(2)][A/B(2)] subtiles of 256 rows x 32 u16, with the
// proven chunk-XOR swizzle (pre-swizzled global source, linear gload_lds dest,
// (kc^sel) read offset -> 0 bank conflicts).
// Schedule: 8 phases / 2 K-tiles, counted vmcnt(4) at phases 4 & 8 only, raw
// s_barrier (NOT __syncthreads -> no vmcnt(0) drain), setprio around MFMA.
template<int NBN, bool RELUQK, typename OutT>
__global__ __launch_bounds__(512, 2) void gemm256(
    const u16* __restrict__ A, const u16* __restrict__ Bt,
    const float* __restrict__ bias, OutT* __restrict__ C)
{
    constexpr int NWG   = 64 * NBN;     // M/256 = 64 row-blocks
    constexpr int NCOLS = NBN * 256;
    __shared__ alignas(16) u16 lds[65536];   // 131072 B

    // XCD-bijective swizzle (NWG % 8 == 0), n-fastest inside a chunk.
    const int bid = blockIdx.x;
    const int wg  = (bid & 7) * (NWG / 8) + (bid >> 3);
    const long m0 = (long)(wg / NBN) * 256;
    const long n0 = (long)(wg % NBN) * 256;

    const int tid  = threadIdx.x;
    const int wave = tid >> 6, lane = tid & 63;
    const int wm = wave >> 2, wn = wave & 3;

    // ---- staging addresses (per thread, 2 loads per half-tile) ----
    const int srow = wave * 32 + (lane >> 2);                 // rows srow, srow+16
    const int gch  = ((lane & 3) ^ ((lane >> 3) & 3)) * 8;    // pre-swizzled k-chunk
    const u16* pA0 = A  + (m0 + srow) * 1024 + gch;
    const u16* pA1 = pA0 + 16 * 1024;
    const u16* pB0 = Bt + (n0 + srow) * 1024 + gch;
    const u16* pB1 = pB0 + 16 * 1024;

    #define SUB(b_,kh_,ab_) (lds + (((b_)*2+(kh_))*2+(ab_))*8192)
    #define STG_A(b_,kh_,t_) { const int k0_ = (t_)*64 + (kh_)*32;            \
        u16* d_ = SUB(b_,kh_,0) + wave * 1024;                                \
        gload_lds16(pA0 + k0_, d_); gload_lds16(pA1 + k0_, d_ + 512); }
    #define STG_B(b_,kh_,t_) { const int k0_ = (t_)*64 + (kh_)*32;            \
        u16* d_ = SUB(b_,kh_,1) + wave * 1024;                                \
        gload_lds16(pB0 + k0_, d_); gload_lds16(pB1 + k0_, d_ + 512); }

    // ---- fragment read addresses ----
    const int m  = lane & 15, kc = lane >> 4;
    const int off  = (kc ^ ((m >> 1) & 3)) * 8;               // de-swizzle
    const int arow = (wm * 128 + m) * 32 + off;               // + mt*512
    const int brow = (wn * 64  + m) * 32 + off;               // + nh*1024 + j*512

    f32x4  acc[8][4] = {};
    bf16x8 af[8];
    bf16x8 b0, b1;

    #define DSA(b_,kh_) { const u16* s_ = SUB(b_,kh_,0);                      \
        _Pragma("unroll") for (int mt_ = 0; mt_ < 8; ++mt_)                   \
            af[mt_] = *(const bf16x8*)(s_ + arow + mt_ * 512); }
    #define DSB(b_,kh_,nh_) { const u16* s_ = SUB(b_,kh_,1) + brow + (nh_)*1024; \
        b0 = *(const bf16x8*)(s_); b1 = *(const bf16x8*)(s_ + 512); }
    #define MM(nh_) { _Pragma("unroll") for (int mt_ = 0; mt_ < 8; ++mt_) {   \
        acc[mt_][(nh_)*2]   = __builtin_amdgcn_mfma_f32_16x16x32_bf16(        \
            af[mt_], b0, acc[mt_][(nh_)*2],   0, 0, 0);                       \
        acc[mt_][(nh_)*2+1] = __builtin_amdgcn_mfma_f32_16x16x32_bf16(        \
            af[mt_], b1, acc[mt_][(nh_)*2+1], 0, 0, 0); } }
    #define BARMM(nh_)                                                        \
        __builtin_amdgcn_s_barrier();                                         \
        asm volatile("s_waitcnt lgkmcnt(0)" ::: "memory");                    \
        __builtin_amdgcn_s_setprio(1);                                        \
        MM(nh_);                                                              \
        __builtin_amdgcn_s_setprio(0);                                        \
        __builtin_amdgcn_s_barrier();

    // ---- prologue: tile0 (both k-halves) + tile1 k-half0; allow last 4 in flight
    STG_A(0,0,0); STG_B(0,0,0);
    STG_A(0,1,0); STG_B(0,1,0);
    STG_A(1,0,1); STG_B(1,0,1);
    asm volatile("s_waitcnt vmcnt(4)" ::: "memory");
    __builtin_amdgcn_s_barrier();

    // ---- main loop: 8 iterations x 2 K-tiles (tile 2i in buf0, 2i+1 in buf1)
    #pragma unroll 1
    for (int i = 0; i < 8; ++i) {
        const int  t1   = 2 * i + 1;
        const bool more = (i < 7);
        // P1 (buf0, kh0, nh0) | stage A kh1(t1) -> buf1
        DSA(0,0); DSB(0,0,0);
        STG_A(1,1,t1);
        BARMM(0);
        // P2 (buf0, kh0, nh1) | stage B kh1(t1)
        DSB(0,0,1);
        STG_B(1,1,t1);
        BARMM(1);
        // P3 (buf0, kh1, nh0) | stage A kh0(t1+1) -> buf0 (kh0 freed at P2)
        DSA(0,1); DSB(0,1,0);
        if (more) STG_A(0,0,t1+1);
        BARMM(0);
        // P4 (buf0, kh1, nh1) | stage B kh0(t1+1); counted wait
        DSB(0,1,1);
        if (more) {
            STG_B(0,0,t1+1);
            asm volatile("s_waitcnt vmcnt(4)" ::: "memory");
        } else {
            asm volatile("s_waitcnt vmcnt(0)" ::: "memory");
        }
        BARMM(1);
        // P5 (buf1, kh0, nh0) | stage A kh1(t1+1) -> buf0 (kh1 freed at P4)
        DSA(1,0); DSB(1,0,0);
        if (more) STG_A(0,1,t1+1);
        BARMM(0);
        // P6 (buf1, kh0, nh1) | stage B kh1(t1+1)
        DSB(1,0,1);
        if (more) STG_B(0,1,t1+1);
        BARMM(1);
        // P7 (buf1, kh1, nh0) | stage A kh0(t1+2) -> buf1 (kh0 freed at P6)
        DSA(1,1); DSB(1,1,0);
        if (more) STG_A(1,0,t1+2);
        BARMM(0);
        // P8 (buf1, kh1, nh1) | stage B kh0(t1+2); counted wait
        DSB(1,1,1);
        if (more) {
            STG_B(1,0,t1+2);
            asm volatile("s_waitcnt vmcnt(4)" ::: "memory");
        }
        BARMM(1);
    }

    // ---- epilogue: C write (bias, optional relu*1/sqrt(32) for q'/k' cols)
    const bool dorelu = RELUQK && (n0 < 1024);
    const int cr = wm * 128 + kc * 4;
    const int cc = wn * 64 + m;
    #pragma unroll
    for (int nf = 0; nf < 4; ++nf) {
        const long gcol = n0 + cc + nf * 16;
        const float bval = bias[gcol];
        #pragma unroll
        for (int mt = 0; mt < 8; ++mt) {
            #pragma unroll
            for (int r = 0; r < 4; ++r) {
                float c = acc[mt][nf][r] + bval;
                if (dorelu) c = fmaxf(c, 0.f) * 0.17677669529663687f;  // 1/sqrt(32)
                OutT* dst = &C[(m0 + cr + mt * 16 + r) * (long)NCOLS + gcol];
                if constexpr (sizeof(OutT) == 2) *dst = f2bf(c);
                else                             *dst = c;
            }
        }
    }
    #undef SUB
    #undef STG_A
    #undef STG_B
    #undef DSA
    #undef DSB
    #undef MM
    #undef BARMM
}

// ---------------------------------------------------------------- kv v3: LDS k-tile, 64-row chunks, partials (no atomics)
// grid (bh=64, chunk=64). part_kv[bh][chunk][f][d], part_ks[bh][chunk][f].
__global__ __launch_bounds__(256) void kv_v3(const u16* __restrict__ Y,
                                             float* __restrict__ part_kv,
                                             float* __restrict__ part_ks)
{
    __shared__ alignas(16) u16 ks[64 * 32];   // [local_row][f]
    const int bh = blockIdx.x, c = blockIdx.y;
    const int b = bh >> 4, h = bh & 15;
    const int tid = threadIdx.x;
    const long rbase = (long)b * 4096 + (long)c * 64;

    // stage k' tile: one bf16x8 per thread
    {
        const int lr = tid >> 2, cc = (tid & 3) * 8;
        *(bf16x8*)&ks[lr * 32 + cc] =
            *(const bf16x8*)(Y + (rbase + lr) * 2048 + 512 + h * 32 + cc);
    }
    __syncthreads();

    const int f = tid >> 3, dg = (tid & 7) * 8;
    const u16* vp = Y + rbase * 2048 + 1024 + h * 64 + dg;
    float acc[8] = {};
    float ksacc = 0.f;
    #pragma unroll 4
    for (int n = 0; n < 64; n++) {
        const float kf = bf2f(ks[n * 32 + f]);
        bf16x8 vv = *(const bf16x8*)(vp + (long)n * 2048);
        #pragma unroll
        for (int j = 0; j < 8; j++) acc[j] += kf * bf2f((u16)vv[j]);
        ksacc += kf;
    }

    float* o = part_kv + (((long)bh * 64 + c) * 32 + f) * 64 + dg;
    *(f32x4*)o       = f32x4{acc[0], acc[1], acc[2], acc[3]};
    *(f32x4*)(o + 4) = f32x4{acc[4], acc[5], acc[6], acc[7]};
    if ((tid & 7) == 0) part_ks[(bh * 64 + c) * 32 + f] = ksacc;
}

// reduce 64 partials -> kv[bh][f][d] (blocks 0..511) and ksum[bh][f] (512..519)
__global__ __launch_bounds__(256) void kv_reduce(const float* __restrict__ part_kv,
                                                 const float* __restrict__ part_ks,
                                                 float* __restrict__ kv,
                                                 float* __restrict__ ksum)
{
    const int idx = blockIdx.x * 256 + threadIdx.x;
    if (blockIdx.x < 512) {                       // 131072 kv elements
        const int bh = idx >> 11, off = idx & 2047;
        const float* p = part_kv + (long)bh * 131072 + off;
        float s = 0.f;
        #pragma unroll 8
        for (int c = 0; c < 64; c++) s += p[c * 2048];
        kv[idx] = s;
    } else {                                      // 2048 ksum elements
        const int i2 = idx - 512 * 256;
        const int bh = i2 >> 5, f = i2 & 31;
        const float* p = part_ks + bh * 64 * 32 + f;
        float s = 0.f;
        #pragma unroll 8
        for (int c = 0; c < 64; c++) s += p[c * 32];
        ksum[i2] = s;
    }
}

// ---------------------------------------------------------------- attn v2: block-tiled, kv in registers
__global__ __launch_bounds__(256) void attn_v2(const u16* __restrict__ Y,
                                               const float* __restrict__ kv,
                                               const float* __restrict__ ksum,
                                               u16* __restrict__ attn)
{
    __shared__ alignas(16) u16 qs[64 * 32];   // [local_row][f]
    __shared__ float zs[64];                  // 1/(den+eps) per local row
    const int tid = threadIdx.x;
    const int bh = blockIdx.x;
    const int b = bh >> 4, h = bh & 15;
    const long row0 = (long)b * 4096 + (long)blockIdx.y * 64;

    {
        const int lr = tid >> 2, c = (tid & 3) * 8;
        *(bf16x8*)&qs[lr * 32 + c] =
            *(const bf16x8*)(Y + (row0 + lr) * 2048 + h * 32 + c);
    }

    const int wave = tid >> 6, lane = tid & 63;
    const float* kvg = kv + (long)bh * 2048 + lane;
    float kvreg[32];
    #pragma unroll
    for (int ff = 0; ff < 32; ff++) kvreg[ff] = kvg[ff * 64];

    __syncthreads();

    {
        const int lr = wave * 16 + (lane & 15);
        const float* ks = ksum + bh * 32;
        float den = 0.f;
        #pragma unroll
        for (int fc = 0; fc < 4; fc++) {
            bf16x8 qv = *(const bf16x8*)&qs[lr * 32 + fc * 8];
            #pragma unroll
            for (int j = 0; j < 8; j++) den += bf2f((u16)qv[j]) * ks[fc * 8 + j];
        }
        if (lane < 16) zs[lr] = 1.f / (den + 1e-8f);
    }
    __syncthreads();

    #pragma unroll
    for (int rg = 0; rg < 4; rg++) {
        const int lr0 = wave * 16 + rg * 4;
        float acc0 = 0.f, acc1 = 0.f, acc2 = 0.f, acc3 = 0.f;
        #pragma unroll
        for (int fc = 0; fc < 4; fc++) {
            bf16x8 q0 = *(const bf16x8*)&qs[(lr0 + 0) * 32 + fc * 8];
            bf16x8 q1 = *(const bf16x8*)&qs[(lr0 + 1) * 32 + fc * 8];
            bf16x8 q2 = *(const bf16x8*)&qs[(lr0 + 2) * 32 + fc * 8];
            bf16x8 q3 = *(const bf16x8*)&qs[(lr0 + 3) * 32 + fc * 8];
            #pragma unroll
            for (int j = 0; j < 8; j++) {
                const float kvf = kvreg[fc * 8 + j];
                acc0 += bf2f((u16)q0[j]) * kvf;
                acc1 += bf2f((u16)q1[j]) * kvf;
                acc2 += bf2f((u16)q2[j]) * kvf;
                acc3 += bf2f((u16)q3[j]) * kvf;
            }
        }
        u16* op = attn + (row0 + lr0) * 1024 + h * 64 + lane;
        op[0]        = f2bf(acc0 * zs[lr0 + 0]);
        op[1024]     = f2bf(acc1 * zs[lr0 + 1]);
        op[2 * 1024] = f2bf(acc2 * zs[lr0 + 2]);
        op[3 * 1024] = f2bf(acc3 * zs[lr0 + 3]);
    }
}

// ---------------------------------------------------------------- launch
extern "C" void kernel_launch(void* const* d_in, const int* in_sizes, int n_in,
                              void* d_out, int out_size, void* d_ws, size_t ws_size,
                              hipStream_t stream)
{
    const float* x    = (const float*)d_in[0];
    const float* Wq   = (const float*)d_in[1];
    const float* bq   = (const float*)d_in[2];
    const float* Wk   = (const float*)d_in[3];
    const float* bk   = (const float*)d_in[4];
    const float* Wv   = (const float*)d_in[5];
    const float* bv   = (const float*)d_in[6];
    const float* proj = (const float*)d_in[7];
    const float* Wo   = (const float*)d_in[8];
    const float* bo   = (const float*)d_in[9];

    // Region w+0 (33.5 MB) is time-multiplexed: xbf (dies at gemm_qkv) ->
    // part_kv (kv_v3..kv_reduce) -> attn (attn_v2..gemm_out).
    char* w = (char*)d_ws;
    u16*   xbf     = (u16*)  (w);                  // 33,554,432 B
    float* part_kv = (float*)(w);                  // alias
    u16*   attn    = (u16*)  (w);                  // alias
    u16*   wallT   = (u16*)  (w + 33554432);       //  4,194,304 B
    u16*   woT     = (u16*)  (w + 37748736);       //  2,097,152 B
    float* bias    = (float*)(w + 39845888);       //      8,192 B
    float* kv      = (float*)(w + 39854080);       //    524,288 B
    float* ksum    = (float*)(w + 40378368);       //      8,192 B
    u16*   Y       = (u16*)  (w + 40386560);       // 67,108,864 B
    float* part_ks = (float*)(w + 107495424);      //    524,288 B (~108 MB total)

    cast_x<<<8192, 256, 0, stream>>>((const float4*)x, (bf16x8*)xbf);

    fold_weights<<<3072, 256, 0, stream>>>(Wq, Wk, Wv, Wo, bq, bk, bv, proj,
                                           wallT, woT, bias);

    gemm256<8, true, u16><<<512, 512, 0, stream>>>(xbf, wallT, bias, Y);

    kv_v3<<<dim3(64, 64), 256, 0, stream>>>(Y, part_kv, part_ks);

    kv_reduce<<<520, 256, 0, stream>>>(part_kv, part_ks, kv, ksum);

    attn_v2<<<dim3(64, 64), 256, 0, stream>>>(Y, kv, ksum, attn);

    gemm256<4, false, float><<<256, 512, 0, stream>>>(attn, woT, bo, (float*)d_out);
}

// Round 2
// 366.458 us; speedup vs baseline: 1.1806x; 1.1167x over previous
//
#include <hip/hip_runtime.h>

typedef unsigned short u16;
typedef __attribute__((ext_vector_type(8))) short bf16x8;
typedef __attribute__((ext_vector_type(4))) float f32x4;

__device__ inline float bf2f(u16 u) {
    unsigned v = ((unsigned)u) << 16;
    return __builtin_bit_cast(float, v);
}
__device__ inline u16 f2bf(float f) {
    unsigned u = __builtin_bit_cast(unsigned, f);
    u += 0x7fff + ((u >> 16) & 1);   // RNE
    return (u16)(u >> 16);
}

// async global->LDS, 16B per lane. LDS dest = wave-uniform base + lane*16.
__device__ inline void gload_lds16(const void* g, void* l) {
    __builtin_amdgcn_global_load_lds(
        (const __attribute__((address_space(1))) unsigned int*)(unsigned long long)g,
        (__attribute__((address_space(3))) unsigned int*)(unsigned)(unsigned long long)l,
        16, 0, 0);
}

// ---------------------------------------------------------------- cast x -> bf16 (8 floats/thread, one 16B store)
__global__ __launch_bounds__(256) void cast_x(const float4* __restrict__ x,
                                              bf16x8* __restrict__ xb) {
    long i = (long)blockIdx.x * 256 + threadIdx.x;
    float4 v0 = x[2 * i];
    float4 v1 = x[2 * i + 1];
    bf16x8 o;
    o[0] = (short)f2bf(v0.x); o[1] = (short)f2bf(v0.y);
    o[2] = (short)f2bf(v0.z); o[3] = (short)f2bf(v0.w);
    o[4] = (short)f2bf(v1.x); o[5] = (short)f2bf(v1.y);
    o[6] = (short)f2bf(v1.z); o[7] = (short)f2bf(v1.w);
    xb[i] = o;
}

// ---------------------------------------------------------------- weight fold/transpose (f32 inputs)
// r < 1024: Wq/Wk folded with proj (coalesced row reads, unchanged).
// r 1024..1279: Wv 64x64 LDS tile-transpose -> WallT rows 1024..2047.
// r 1280..1535: Wo 64x64 LDS tile-transpose -> WoT.
__global__ __launch_bounds__(256) void fold_weights(
    const float* __restrict__ Wq, const float* __restrict__ Wk,
    const float* __restrict__ Wv, const float* __restrict__ Wo,
    const float* __restrict__ bq, const float* __restrict__ bk,
    const float* __restrict__ bv, const float* __restrict__ proj,
    u16* __restrict__ WallT, u16* __restrict__ WoT, float* __restrict__ bias_all)
{
    const int r = blockIdx.x;
    const int tid = threadIdx.x;
    if (r < 1024) {
        const float* W  = (r < 512) ? Wq : Wk;
        const float* bb = (r < 512) ? bq : bk;
        const int h = (r & 511) >> 5, f = r & 31;
        __shared__ float pcol[64];
        if (tid < 64) pcol[tid] = proj[tid * 32 + f];
        __syncthreads();
        for (int it = 0; it < 4; it++) {
            const int kin = it * 256 + tid;
            const float* wrow = W + (long)kin * 1024 + h * 64;
            float acc = 0.f;
            #pragma unroll
            for (int d = 0; d < 64; d += 4) {
                float4 w = *(const float4*)(wrow + d);
                acc += w.x * pcol[d] + w.y * pcol[d + 1] + w.z * pcol[d + 2] + w.w * pcol[d + 3];
            }
            WallT[(long)r * 1024 + kin] = f2bf(acc);
        }
        if (tid == 0) {
            float a = 0.f;
            for (int d = 0; d < 64; d++) a += bb[h * 64 + d] * pcol[d];
            bias_all[r] = a;
        }
    } else {
        const bool isV = (r < 1280);
        const int tile = isV ? (r - 1024) : (r - 1280);
        const int kt = tile >> 4, ct = tile & 15;     // 16x16 tiles of 64x64
        const float* src = isV ? Wv : Wo;
        __shared__ float T[64][65];
        #pragma unroll
        for (int it = 0; it < 16; ++it) {
            const int kl = it * 4 + (tid >> 6);
            T[kl][tid & 63] = src[(long)(kt * 64 + kl) * 1024 + ct * 64 + (tid & 63)];
        }
        __syncthreads();
        #pragma unroll
        for (int it = 0; it < 2; ++it) {
            const int li = it * 256 + tid;
            const int cl = li >> 3, k8 = (li & 7) * 8;
            bf16x8 o;
            #pragma unroll
            for (int j = 0; j < 8; ++j) o[j] = (short)f2bf(T[k8 + j][cl]);
            u16* dst = isV ? (WallT + (long)(1024 + ct * 64 + cl) * 1024)
                           : (WoT   + (long)(ct * 64 + cl) * 1024);
            *(bf16x8*)&dst[kt * 64 + k8] = o;
        }
        if (isV && kt == 0 && tid < 64) bias_all[1024 + ct * 64 + tid] = bv[ct * 64 + tid];
    }
}

// ---------------------------------------------------------------- 256x256 8-phase pipelined bf16 MFMA GEMM
// K=1024 fixed. B transposed [N][K]. 512 threads = 8 waves (2m x 4n), per-wave
// output 128x64 (8 m-frags x 4 n-frags of 16x16x32 MFMA).
// LDS 128KiB: [buf(2)][khalf(2)][A/B(2)] subtiles of 256 rows x 32 u16 (chunk-XOR
// swizzle: pre-swizzled global source, linear gload_lds dest, (kc^sel) read).
// Schedule: 8 phases / 2 K-tiles, counted vmcnt(4) at phases 4 & 8, raw s_barrier,
// setprio around MFMA. Epilogue: C tile staged in LDS (swizzled), coalesced 16B
// stores (fixes 2x HBM write amplification of the scalar-store epilogue).
template<int NBN, bool RELUQK, typename OutT>
__global__ __launch_bounds__(512, 2) void gemm256(
    const u16* __restrict__ A, const u16* __restrict__ Bt,
    const float* __restrict__ bias, OutT* __restrict__ C)
{
    constexpr int NWG   = 64 * NBN;     // M/256 = 64 row-blocks
    constexpr int NCOLS = NBN * 256;
    __shared__ alignas(16) u16 lds[65536];   // 131072 B

    // XCD-bijective swizzle (NWG % 8 == 0), n-fastest inside a chunk.
    const int bid = blockIdx.x;
    const int wg  = (bid & 7) * (NWG / 8) + (bid >> 3);
    const long m0 = (long)(wg / NBN) * 256;
    const long n0 = (long)(wg % NBN) * 256;

    const int tid  = threadIdx.x;
    const int wave = tid >> 6, lane = tid & 63;
    const int wm = wave >> 2, wn = wave & 3;

    // ---- staging addresses (per thread, 2 loads per half-tile) ----
    const int srow = wave * 32 + (lane >> 2);                 // rows srow, srow+16
    const int gch  = ((lane & 3) ^ ((lane >> 3) & 3)) * 8;    // pre-swizzled k-chunk
    const u16* pA0 = A  + (m0 + srow) * 1024 + gch;
    const u16* pA1 = pA0 + 16 * 1024;
    const u16* pB0 = Bt + (n0 + srow) * 1024 + gch;
    const u16* pB1 = pB0 + 16 * 1024;

    #define SUB(b_,kh_,ab_) (lds + (((b_)*2+(kh_))*2+(ab_))*8192)
    #define STG_A(b_,kh_,t_) { const int k0_ = (t_)*64 + (kh_)*32;            \
        u16* d_ = SUB(b_,kh_,0) + wave * 1024;                                \
        gload_lds16(pA0 + k0_, d_); gload_lds16(pA1 + k0_, d_ + 512); }
    #define STG_B(b_,kh_,t_) { const int k0_ = (t_)*64 + (kh_)*32;            \
        u16* d_ = SUB(b_,kh_,1) + wave * 1024;                                \
        gload_lds16(pB0 + k0_, d_); gload_lds16(pB1 + k0_, d_ + 512); }

    // ---- fragment read addresses ----
    const int m  = lane & 15, kc = lane >> 4;
    const int off  = (kc ^ ((m >> 1) & 3)) * 8;               // de-swizzle
    const int arow = (wm * 128 + m) * 32 + off;               // + mt*512
    const int brow = (wn * 64  + m) * 32 + off;               // + nh*1024 + j*512

    f32x4  acc[8][4] = {};
    bf16x8 af[8];
    bf16x8 b0, b1;

    #define DSA(b_,kh_) { const u16* s_ = SUB(b_,kh_,0);                      \
        _Pragma("unroll") for (int mt_ = 0; mt_ < 8; ++mt_)                   \
            af[mt_] = *(const bf16x8*)(s_ + arow + mt_ * 512); }
    #define DSB(b_,kh_,nh_) { const u16* s_ = SUB(b_,kh_,1) + brow + (nh_)*1024; \
        b0 = *(const bf16x8*)(s_); b1 = *(const bf16x8*)(s_ + 512); }
    #define MM(nh_) { _Pragma("unroll") for (int mt_ = 0; mt_ < 8; ++mt_) {   \
        acc[mt_][(nh_)*2]   = __builtin_amdgcn_mfma_f32_16x16x32_bf16(        \
            af[mt_], b0, acc[mt_][(nh_)*2],   0, 0, 0);                       \
        acc[mt_][(nh_)*2+1] = __builtin_amdgcn_mfma_f32_16x16x32_bf16(        \
            af[mt_], b1, acc[mt_][(nh_)*2+1], 0, 0, 0); } }
    #define BARMM(nh_)                                                        \
        __builtin_amdgcn_s_barrier();                                         \
        asm volatile("s_waitcnt lgkmcnt(0)" ::: "memory");                    \
        __builtin_amdgcn_s_setprio(1);                                        \
        MM(nh_);                                                              \
        __builtin_amdgcn_s_setprio(0);                                        \
        __builtin_amdgcn_s_barrier();

    // ---- prologue: tile0 (both k-halves) + tile1 k-half0; allow last 4 in flight
    STG_A(0,0,0); STG_B(0,0,0);
    STG_A(0,1,0); STG_B(0,1,0);
    STG_A(1,0,1); STG_B(1,0,1);
    asm volatile("s_waitcnt vmcnt(4)" ::: "memory");
    __builtin_amdgcn_s_barrier();

    // ---- main loop: 8 iterations x 2 K-tiles (tile 2i in buf0, 2i+1 in buf1)
    #pragma unroll 1
    for (int i = 0; i < 8; ++i) {
        const int  t1   = 2 * i + 1;
        const bool more = (i < 7);
        // P1 (buf0, kh0, nh0) | stage A kh1(t1) -> buf1
        DSA(0,0); DSB(0,0,0);
        STG_A(1,1,t1);
        BARMM(0);
        // P2 (buf0, kh0, nh1) | stage B kh1(t1)
        DSB(0,0,1);
        STG_B(1,1,t1);
        BARMM(1);
        // P3 (buf0, kh1, nh0) | stage A kh0(t1+1) -> buf0 (kh0 freed at P2)
        DSA(0,1); DSB(0,1,0);
        if (more) STG_A(0,0,t1+1);
        BARMM(0);
        // P4 (buf0, kh1, nh1) | stage B kh0(t1+1); counted wait
        DSB(0,1,1);
        if (more) {
            STG_B(0,0,t1+1);
            asm volatile("s_waitcnt vmcnt(4)" ::: "memory");
        } else {
            asm volatile("s_waitcnt vmcnt(0)" ::: "memory");
        }
        BARMM(1);
        // P5 (buf1, kh0, nh0) | stage A kh1(t1+1) -> buf0 (kh1 freed at P4)
        DSA(1,0); DSB(1,0,0);
        if (more) STG_A(0,1,t1+1);
        BARMM(0);
        // P6 (buf1, kh0, nh1) | stage B kh1(t1+1)
        DSB(1,0,1);
        if (more) STG_B(0,1,t1+1);
        BARMM(1);
        // P7 (buf1, kh1, nh0) | stage A kh0(t1+2) -> buf1 (kh0 freed at P6)
        DSA(1,1); DSB(1,1,0);
        if (more) STG_A(1,0,t1+2);
        BARMM(0);
        // P8 (buf1, kh1, nh1) | stage B kh0(t1+2); counted wait
        DSB(1,1,1);
        if (more) {
            STG_B(1,0,t1+2);
            asm volatile("s_waitcnt vmcnt(4)" ::: "memory");
        }
        BARMM(1);
    }

    // ---- epilogue via LDS: coalesced 16B stores, no write amplification ----
    if constexpr (sizeof(OutT) == 2) {
        const bool dorelu = RELUQK && (n0 < 1024);
        #pragma unroll
        for (int nf = 0; nf < 4; ++nf) {
            const int col = wn * 64 + nf * 16 + m;
            const float bval = bias[n0 + col];
            #pragma unroll
            for (int mt = 0; mt < 8; ++mt) {
                #pragma unroll
                for (int r = 0; r < 4; ++r) {
                    const int row = wm * 128 + mt * 16 + kc * 4 + r;
                    float c = acc[mt][nf][r] + bval;
                    if (dorelu) c = fmaxf(c, 0.f) * 0.17677669529663687f;  // 1/sqrt(32)
                    const int x = ((row >> 2) & 7) << 1;
                    lds[row * 256 + (((col >> 3) ^ x) << 3) + (col & 7)] = f2bf(c);
                }
            }
        }
        __syncthreads();
        #pragma unroll
        for (int it = 0; it < 16; ++it) {
            const int li = it * 512 + tid;
            const int row = li >> 5, ch = li & 31;
            const int x = ((row >> 2) & 7) << 1;
            bf16x8 v = *(const bf16x8*)&lds[row * 256 + ((ch ^ x) << 3)];
            *(bf16x8*)&C[(m0 + row) * (long)NCOLS + n0 + ch * 8] = v;
        }
    } else {
        float* ft = (float*)lds;                 // 128 rows x 256 f32 = 128 KiB/half
        #pragma unroll 1
        for (int half = 0; half < 2; ++half) {
            __syncthreads();
            if (wm == half) {
                #pragma unroll
                for (int nf = 0; nf < 4; ++nf) {
                    const int col = wn * 64 + nf * 16 + m;
                    const float bval = bias[n0 + col];
                    #pragma unroll
                    for (int mt = 0; mt < 8; ++mt) {
                        #pragma unroll
                        for (int r = 0; r < 4; ++r) {
                            const int row = mt * 16 + kc * 4 + r;   // 0..127
                            const int x = ((row >> 2) & 7) << 1;
                            ft[row * 256 + (((col >> 2) ^ x) << 2) + (col & 3)] =
                                acc[mt][nf][r] + bval;
                        }
                    }
                }
            }
            __syncthreads();
            #pragma unroll
            for (int it = 0; it < 16; ++it) {
                const int li = it * 512 + tid;
                const int row = li >> 6, ch = li & 63;
                const int x = ((row >> 2) & 7) << 1;
                float4 v = *(const float4*)&ft[row * 256 + ((ch ^ x) << 2)];
                *(float4*)&C[(m0 + half * 128 + row) * (long)NCOLS + n0 + ch * 4] = v;
            }
        }
    }
    #undef SUB
    #undef STG_A
    #undef STG_B
    #undef DSA
    #undef DSB
    #undef MM
    #undef BARMM
}

// ---------------------------------------------------------------- kv v4: 128-row chunks, f32 LDS tiles (no per-fma cvt)
// grid (bh=64, chunk=32). part_kv[bh][chunk][f][d], part_ks[bh][chunk][f].
__global__ __launch_bounds__(256) void kv_v3(const u16* __restrict__ Y,
                                             float* __restrict__ part_kv,
                                             float* __restrict__ part_ks)
{
    __shared__ float ksf[128 * 33];   // [n][f] f32, pad 33
    __shared__ float vsf[128 * 68];   // [n][d] f32, pad 68 (16B-aligned rows)
    const int bh = blockIdx.x, c = blockIdx.y;
    const int b = bh >> 4, h = bh & 15;
    const int tid = threadIdx.x;
    const long rbase = (long)b * 4096 + (long)c * 128;

    #pragma unroll
    for (int it = 0; it < 2; ++it) {
        const int lr = it * 64 + (tid >> 2), cc = (tid & 3) * 8;
        bf16x8 kx = *(const bf16x8*)(Y + (rbase + lr) * 2048 + 512 + h * 32 + cc);
        #pragma unroll
        for (int j = 0; j < 8; ++j) ksf[lr * 33 + cc + j] = bf2f((u16)kx[j]);
    }
    #pragma unroll
    for (int it = 0; it < 4; ++it) {
        const int lr = it * 32 + (tid >> 3), cc = (tid & 7) * 8;
        bf16x8 vx = *(const bf16x8*)(Y + (rbase + lr) * 2048 + 1024 + h * 64 + cc);
        #pragma unroll
        for (int j = 0; j < 8; ++j) vsf[lr * 68 + cc + j] = bf2f((u16)vx[j]);
    }
    __syncthreads();

    const int f = tid >> 3, dg = (tid & 7) * 8;
    float acc[8] = {};
    float ksacc = 0.f;
    #pragma unroll 4
    for (int n = 0; n < 128; ++n) {
        const float kf = ksf[n * 33 + f];
        const float4 v0 = *(const float4*)&vsf[n * 68 + dg];
        const float4 v1 = *(const float4*)&vsf[n * 68 + dg + 4];
        acc[0] += kf * v0.x; acc[1] += kf * v0.y;
        acc[2] += kf * v0.z; acc[3] += kf * v0.w;
        acc[4] += kf * v1.x; acc[5] += kf * v1.y;
        acc[6] += kf * v1.z; acc[7] += kf * v1.w;
        ksacc += kf;
    }

    float* o = part_kv + (((long)bh * 32 + c) * 32 + f) * 64 + dg;
    *(f32x4*)o       = f32x4{acc[0], acc[1], acc[2], acc[3]};
    *(f32x4*)(o + 4) = f32x4{acc[4], acc[5], acc[6], acc[7]};
    if ((tid & 7) == 0) part_ks[(bh * 32 + c) * 32 + f] = ksacc;
}

// reduce 32 partials -> kv[bh][f][d] (blocks 0..511) and ksum[bh][f] (512..519)
__global__ __launch_bounds__(256) void kv_reduce(const float* __restrict__ part_kv,
                                                 const float* __restrict__ part_ks,
                                                 float* __restrict__ kv,
                                                 float* __restrict__ ksum)
{
    const int idx = blockIdx.x * 256 + threadIdx.x;
    if (blockIdx.x < 512) {                       // 131072 kv elements
        const int bh = idx >> 11, off = idx & 2047;
        const float* p = part_kv + (long)bh * 65536 + off;
        float s = 0.f;
        #pragma unroll 8
        for (int c = 0; c < 32; c++) s += p[c * 2048];
        kv[idx] = s;
    } else {                                      // 2048 ksum elements
        const int i2 = idx - 512 * 256;
        const int bh = i2 >> 5, f = i2 & 31;
        const float* p = part_ks + bh * 1024 + f;
        float s = 0.f;
        #pragma unroll 8
        for (int c = 0; c < 32; c++) s += p[c * 32];
        ksum[i2] = s;
    }
}

// ---------------------------------------------------------------- attn v3: f32 LDS q-tile, kv in registers
__global__ __launch_bounds__(256) void attn_v2(const u16* __restrict__ Y,
                                               const float* __restrict__ kv,
                                               const float* __restrict__ ksum,
                                               u16* __restrict__ attn)
{
    __shared__ float qsf[64 * 36];    // [row][f] f32, pad 36 (16B-aligned rows)
    __shared__ float kss[32];
    __shared__ float zs[64];          // 1/(den+eps) per local row
    const int tid = threadIdx.x;
    const int bh = blockIdx.x;
    const int b = bh >> 4, h = bh & 15;
    const long row0 = (long)b * 4096 + (long)blockIdx.y * 64;

    {
        const int lr = tid >> 2, c8 = (tid & 3) * 8;
        bf16x8 qx = *(const bf16x8*)(Y + (row0 + lr) * 2048 + h * 32 + c8);
        #pragma unroll
        for (int j = 0; j < 8; ++j) qsf[lr * 36 + c8 + j] = bf2f((u16)qx[j]);
    }
    if (tid < 32) kss[tid] = ksum[bh * 32 + tid];

    const int wave = tid >> 6, lane = tid & 63;
    const float* kvg = kv + (long)bh * 2048 + lane;
    float kvreg[32];
    #pragma unroll
    for (int ff = 0; ff < 32; ++ff) kvreg[ff] = kvg[ff * 64];

    __syncthreads();

    {
        const int lr = wave * 16 + (lane & 15);
        float den = 0.f;
        #pragma unroll
        for (int fc = 0; fc < 8; ++fc) {
            const float4 q = *(const float4*)&qsf[lr * 36 + fc * 4];
            den += q.x * kss[fc * 4]     + q.y * kss[fc * 4 + 1]
                 + q.z * kss[fc * 4 + 2] + q.w * kss[fc * 4 + 3];
        }
        if (lane < 16) zs[lr] = 1.f / (den + 1e-8f);
    }
    __syncthreads();

    #pragma unroll
    for (int rg = 0; rg < 4; ++rg) {
        const int lr0 = wave * 16 + rg * 4;
        float acc0 = 0.f, acc1 = 0.f, acc2 = 0.f, acc3 = 0.f;
        #pragma unroll
        for (int fc = 0; fc < 8; ++fc) {
            const float4 q0 = *(const float4*)&qsf[(lr0 + 0) * 36 + fc * 4];
            const float4 q1 = *(const float4*)&qsf[(lr0 + 1) * 36 + fc * 4];
            const float4 q2 = *(const float4*)&qsf[(lr0 + 2) * 36 + fc * 4];
            const float4 q3 = *(const float4*)&qsf[(lr0 + 3) * 36 + fc * 4];
            const float k0 = kvreg[fc * 4], k1 = kvreg[fc * 4 + 1];
            const float k2 = kvreg[fc * 4 + 2], k3 = kvreg[fc * 4 + 3];
            acc0 += q0.x * k0 + q0.y * k1 + q0.z * k2 + q0.w * k3;
            acc1 += q1.x * k0 + q1.y * k1 + q1.z * k2 + q1.w * k3;
            acc2 += q2.x * k0 + q2.y * k1 + q2.z * k2 + q2.w * k3;
            acc3 += q3.x * k0 + q3.y * k1 + q3.z * k2 + q3.w * k3;
        }
        u16* op = attn + (row0 + lr0) * 1024 + h * 64 + lane;
        op[0]        = f2bf(acc0 * zs[lr0 + 0]);
        op[1024]     = f2bf(acc1 * zs[lr0 + 1]);
        op[2 * 1024] = f2bf(acc2 * zs[lr0 + 2]);
        op[3 * 1024] = f2bf(acc3 * zs[lr0 + 3]);
    }
}

// ---------------------------------------------------------------- launch
extern "C" void kernel_launch(void* const* d_in, const int* in_sizes, int n_in,
                              void* d_out, int out_size, void* d_ws, size_t ws_size,
                              hipStream_t stream)
{
    const float* x    = (const float*)d_in[0];
    const float* Wq   = (const float*)d_in[1];
    const float* bq   = (const float*)d_in[2];
    const float* Wk   = (const float*)d_in[3];
    const float* bk   = (const float*)d_in[4];
    const float* Wv   = (const float*)d_in[5];
    const float* bv   = (const float*)d_in[6];
    const float* proj = (const float*)d_in[7];
    const float* Wo   = (const float*)d_in[8];
    const float* bo   = (const float*)d_in[9];

    // Region w+0 (33.5 MB) is time-multiplexed: xbf (dies at gemm_qkv) ->
    // part_kv (kv_v3..kv_reduce, now 16.8 MB) -> attn (attn_v2..gemm_out).
    char* w = (char*)d_ws;
    u16*   xbf     = (u16*)  (w);                  // 33,554,432 B
    float* part_kv = (float*)(w);                  // alias (16,777,216 B used)
    u16*   attn    = (u16*)  (w);                  // alias
    u16*   wallT   = (u16*)  (w + 33554432);       //  4,194,304 B
    u16*   woT     = (u16*)  (w + 37748736);       //  2,097,152 B
    float* bias    = (float*)(w + 39845888);       //      8,192 B
    float* kv      = (float*)(w + 39854080);       //    524,288 B
    float* ksum    = (float*)(w + 40378368);       //      8,192 B
    u16*   Y       = (u16*)  (w + 40386560);       // 67,108,864 B
    float* part_ks = (float*)(w + 107495424);      //    262,144 B used

    cast_x<<<8192, 256, 0, stream>>>((const float4*)x, (bf16x8*)xbf);

    fold_weights<<<1536, 256, 0, stream>>>(Wq, Wk, Wv, Wo, bq, bk, bv, proj,
                                           wallT, woT, bias);

    gemm256<8, true, u16><<<512, 512, 0, stream>>>(xbf, wallT, bias, Y);

    kv_v3<<<dim3(64, 32), 256, 0, stream>>>(Y, part_kv, part_ks);

    kv_reduce<<<520, 256, 0, stream>>>(part_kv, part_ks, kv, ksum);

    attn_v2<<<dim3(64, 64), 256, 0, stream>>>(Y, kv, ksum, attn);

    gemm256<4, false, float><<<256, 512, 0, stream>>>(attn, woT, bo, (float*)d_out);
}

// Round 5
// 318.506 us; speedup vs baseline: 1.3584x; 1.1506x over previous
//
#include <hip/hip_runtime.h>

typedef unsigned short u16;
typedef __attribute__((ext_vector_type(8))) short bf16x8;
typedef __attribute__((ext_vector_type(4))) float f32x4;

__device__ inline float bf2f(u16 u) {
    unsigned v = ((unsigned)u) << 16;
    return __builtin_bit_cast(float, v);
}
__device__ inline u16 f2bf(float f) {
    unsigned u = __builtin_bit_cast(unsigned, f);
    u += 0x7fff + ((u >> 16) & 1);   // RNE
    return (u16)(u >> 16);
}

// async global->LDS, 16B per lane. LDS dest = wave-uniform base + lane*16.
__device__ inline void gload_lds16(const void* g, void* l) {
    __builtin_amdgcn_global_load_lds(
        (const __attribute__((address_space(1))) unsigned int*)(unsigned long long)g,
        (__attribute__((address_space(3))) unsigned int*)(unsigned)(unsigned long long)l,
        16, 0, 0);
}

// ---------------------------------------------------------------- cast x -> bf16 (8 floats/thread, one 16B store)
__global__ __launch_bounds__(256) void cast_x(const float4* __restrict__ x,
                                              bf16x8* __restrict__ xb) {
    long i = (long)blockIdx.x * 256 + threadIdx.x;
    float4 v0 = x[2 * i];
    float4 v1 = x[2 * i + 1];
    bf16x8 o;
    o[0] = (short)f2bf(v0.x); o[1] = (short)f2bf(v0.y);
    o[2] = (short)f2bf(v0.z); o[3] = (short)f2bf(v0.w);
    o[4] = (short)f2bf(v1.x); o[5] = (short)f2bf(v1.y);
    o[6] = (short)f2bf(v1.z); o[7] = (short)f2bf(v1.w);
    xb[i] = o;
}

// ---------------------------------------------------------------- fold Wq/Wk with proj (grid 256)
// block = (qk, h, kt): stage proj (8KB) + 128x64 W panel (32KB) in LDS with
// coalesced reads; each thread computes 16 folded values for column f.
__global__ __launch_bounds__(256) void fold_qk(
    const float* __restrict__ Wq, const float* __restrict__ Wk,
    const float* __restrict__ bq, const float* __restrict__ bk,
    const float* __restrict__ proj,
    u16* __restrict__ WallT, float* __restrict__ bias_all)
{
    const int bid = blockIdx.x;
    const int tid = threadIdx.x;
    const int qk = bid >> 7, h = (bid >> 3) & 15, kt = bid & 7;
    const float* W  = qk ? Wk : Wq;
    const float* bb = qk ? bk : bq;
    const int kin0 = kt * 128;
    __shared__ float pj[64 * 32];       // proj[d][f], 8 KB
    __shared__ float panel[128 * 64];   // W[kin][d] panel, 32 KB
    {
        const float4* ps = (const float4*)proj;
        float4* pd = (float4*)pj;
        #pragma unroll
        for (int it = 0; it < 2; ++it) pd[it * 256 + tid] = ps[it * 256 + tid];
    }
    #pragma unroll
    for (int it = 0; it < 8; ++it) {
        const int li = it * 256 + tid;            // 2048 float4s
        const int row = li >> 4, c4 = (li & 15) * 4;
        *(float4*)&panel[row * 64 + c4] =
            *(const float4*)&W[(long)(kin0 + row) * 1024 + h * 64 + c4];
    }
    __syncthreads();

    const int f = tid & 31, g = tid >> 5;        // 8 groups x 16 kin rows
    float pjr[64];
    #pragma unroll
    for (int d = 0; d < 64; ++d) pjr[d] = pj[d * 32 + f];

    alignas(16) u16 outv[16];
    #pragma unroll
    for (int rr = 0; rr < 16; ++rr) {
        const float4* prow = (const float4*)&panel[(g * 16 + rr) * 64];
        float acc = 0.f;
        #pragma unroll
        for (int d4 = 0; d4 < 16; ++d4) {
            float4 p = prow[d4];
            acc += p.x * pjr[d4 * 4]     + p.y * pjr[d4 * 4 + 1]
                 + p.z * pjr[d4 * 4 + 2] + p.w * pjr[d4 * 4 + 3];
        }
        outv[rr] = f2bf(acc);
    }
    u16* dst = WallT + (long)(qk * 512 + h * 32 + f) * 1024 + kin0 + g * 16;
    *(bf16x8*)dst     = *(const bf16x8*)&outv[0];
    *(bf16x8*)&dst[8] = *(const bf16x8*)&outv[8];

    if (kt == 0 && g == 0) {
        float a = 0.f;
        #pragma unroll
        for (int d = 0; d < 64; ++d) a += bb[h * 64 + d] * pjr[d];
        bias_all[qk * 512 + h * 32 + f] = a;
    }
}

// ---------------------------------------------------------------- transpose Wv/Wo (grid 512)
// bid < 256: Wv 64x64 LDS tile-transpose -> WallT rows 1024..2047.
// bid >= 256: Wo 64x64 LDS tile-transpose -> WoT.
__global__ __launch_bounds__(256) void transpose_vo(
    const float* __restrict__ Wv, const float* __restrict__ Wo,
    const float* __restrict__ bv,
    u16* __restrict__ WallT, u16* __restrict__ WoT, float* __restrict__ bias_all)
{
    const int bid = blockIdx.x;
    const int tid = threadIdx.x;
    const bool isV = (bid < 256);
    const int tile = isV ? bid : (bid - 256);
    const int kt = tile >> 4, ct = tile & 15;     // 16x16 tiles of 64x64
    const float* src = isV ? Wv : Wo;
    __shared__ float T[64][65];
    #pragma unroll
    for (int it = 0; it < 16; ++it) {
        const int kl = it * 4 + (tid >> 6);
        T[kl][tid & 63] = src[(long)(kt * 64 + kl) * 1024 + ct * 64 + (tid & 63)];
    }
    __syncthreads();
    #pragma unroll
    for (int it = 0; it < 2; ++it) {
        const int li = it * 256 + tid;
        const int cl = li >> 3, k8 = (li & 7) * 8;
        bf16x8 o;
        #pragma unroll
        for (int j = 0; j < 8; ++j) o[j] = (short)f2bf(T[k8 + j][cl]);
        u16* dst = isV ? (WallT + (long)(1024 + ct * 64 + cl) * 1024)
                       : (WoT   + (long)(ct * 64 + cl) * 1024);
        *(bf16x8*)&dst[kt * 64 + k8] = o;
    }
    if (isV && kt == 0 && tid < 64) bias_all[1024 + ct * 64 + tid] = bv[ct * 64 + tid];
}

// ---------------------------------------------------------------- 256x256 8-phase pipelined bf16 MFMA GEMM
// K=1024 fixed. B transposed [N][K]. 512 threads = 8 waves (2m x 4n), per-wave
// output 128x64 (8 m-frags x 4 n-frags of 16x16x32 MFMA).
// LDS 128KiB: [buf(2)][khalf(2)][A/B(2)] subtiles of 256 rows x 32 u16 (chunk-XOR
// swizzle: pre-swizzled global source, linear gload_lds dest, (kc^sel) read).
// Schedule: 8 phases / 2 K-tiles, counted vmcnt(4) at phases 4 & 8, raw s_barrier,
// setprio around MFMA. Epilogue: C tile staged in LDS (swizzled), coalesced 16B
// stores (fixes 2x HBM write amplification of the scalar-store epilogue).
template<int NBN, bool RELUQK, typename OutT>
__global__ __launch_bounds__(512, 2) void gemm256(
    const u16* __restrict__ A, const u16* __restrict__ Bt,
    const float* __restrict__ bias, OutT* __restrict__ C)
{
    constexpr int NWG   = 64 * NBN;     // M/256 = 64 row-blocks
    constexpr int NCOLS = NBN * 256;
    __shared__ alignas(16) u16 lds[65536];   // 131072 B

    // XCD-bijective swizzle (NWG % 8 == 0), n-fastest inside a chunk.
    const int bid = blockIdx.x;
    const int wg  = (bid & 7) * (NWG / 8) + (bid >> 3);
    const long m0 = (long)(wg / NBN) * 256;
    const long n0 = (long)(wg % NBN) * 256;

    const int tid  = threadIdx.x;
    const int wave = tid >> 6, lane = tid & 63;
    const int wm = wave >> 2, wn = wave & 3;

    // ---- staging addresses (per thread, 2 loads per half-tile) ----
    const int srow = wave * 32 + (lane >> 2);                 // rows srow, srow+16
    const int gch  = ((lane & 3) ^ ((lane >> 3) & 3)) * 8;    // pre-swizzled k-chunk
    const u16* pA0 = A  + (m0 + srow) * 1024 + gch;
    const u16* pA1 = pA0 + 16 * 1024;
    const u16* pB0 = Bt + (n0 + srow) * 1024 + gch;
    const u16* pB1 = pB0 + 16 * 1024;

    #define SUB(b_,kh_,ab_) (lds + (((b_)*2+(kh_))*2+(ab_))*8192)
    #define STG_A(b_,kh_,t_) { const int k0_ = (t_)*64 + (kh_)*32;            \
        u16* d_ = SUB(b_,kh_,0) + wave * 1024;                                \
        gload_lds16(pA0 + k0_, d_); gload_lds16(pA1 + k0_, d_ + 512); }
    #define STG_B(b_,kh_,t_) { const int k0_ = (t_)*64 + (kh_)*32;            \
        u16* d_ = SUB(b_,kh_,1) + wave * 1024;                                \
        gload_lds16(pB0 + k0_, d_); gload_lds16(pB1 + k0_, d_ + 512); }

    // ---- fragment read addresses ----
    const int m  = lane & 15, kc = lane >> 4;
    const int off  = (kc ^ ((m >> 1) & 3)) * 8;               // de-swizzle
    const int arow = (wm * 128 + m) * 32 + off;               // + mt*512
    const int brow = (wn * 64  + m) * 32 + off;               // + nh*1024 + j*512

    f32x4  acc[8][4] = {};
    bf16x8 af[8];
    bf16x8 b0, b1;

    #define DSA(b_,kh_) { const u16* s_ = SUB(b_,kh_,0);                      \
        _Pragma("unroll") for (int mt_ = 0; mt_ < 8; ++mt_)                   \
            af[mt_] = *(const bf16x8*)(s_ + arow + mt_ * 512); }
    #define DSB(b_,kh_,nh_) { const u16* s_ = SUB(b_,kh_,1) + brow + (nh_)*1024; \
        b0 = *(const bf16x8*)(s_); b1 = *(const bf16x8*)(s_ + 512); }
    #define MM(nh_) { _Pragma("unroll") for (int mt_ = 0; mt_ < 8; ++mt_) {   \
        acc[mt_][(nh_)*2]   = __builtin_amdgcn_mfma_f32_16x16x32_bf16(        \
            af[mt_], b0, acc[mt_][(nh_)*2],   0, 0, 0);                       \
        acc[mt_][(nh_)*2+1] = __builtin_amdgcn_mfma_f32_16x16x32_bf16(        \
            af[mt_], b1, acc[mt_][(nh_)*2+1], 0, 0, 0); } }
    #define BARMM(nh_)                                                        \
        __builtin_amdgcn_s_barrier();                                         \
        asm volatile("s_waitcnt lgkmcnt(0)" ::: "memory");                    \
        __builtin_amdgcn_s_setprio(1);                                        \
        MM(nh_);                                                              \
        __builtin_amdgcn_s_setprio(0);                                        \
        __builtin_amdgcn_s_barrier();

    // ---- prologue: tile0 (both k-halves) + tile1 k-half0; allow last 4 in flight
    STG_A(0,0,0); STG_B(0,0,0);
    STG_A(0,1,0); STG_B(0,1,0);
    STG_A(1,0,1); STG_B(1,0,1);
    asm volatile("s_waitcnt vmcnt(4)" ::: "memory");
    __builtin_amdgcn_s_barrier();

    // ---- main loop: 8 iterations x 2 K-tiles (tile 2i in buf0, 2i+1 in buf1)
    #pragma unroll 1
    for (int i = 0; i < 8; ++i) {
        const int  t1   = 2 * i + 1;
        const bool more = (i < 7);
        // P1 (buf0, kh0, nh0) | stage A kh1(t1) -> buf1
        DSA(0,0); DSB(0,0,0);
        STG_A(1,1,t1);
        BARMM(0);
        // P2 (buf0, kh0, nh1) | stage B kh1(t1)
        DSB(0,0,1);
        STG_B(1,1,t1);
        BARMM(1);
        // P3 (buf0, kh1, nh0) | stage A kh0(t1+1) -> buf0 (kh0 freed at P2)
        DSA(0,1); DSB(0,1,0);
        if (more) STG_A(0,0,t1+1);
        BARMM(0);
        // P4 (buf0, kh1, nh1) | stage B kh0(t1+1); counted wait
        DSB(0,1,1);
        if (more) {
            STG_B(0,0,t1+1);
            asm volatile("s_waitcnt vmcnt(4)" ::: "memory");
        } else {
            asm volatile("s_waitcnt vmcnt(0)" ::: "memory");
        }
        BARMM(1);
        // P5 (buf1, kh0, nh0) | stage A kh1(t1+1) -> buf0 (kh1 freed at P4)
        DSA(1,0); DSB(1,0,0);
        if (more) STG_A(0,1,t1+1);
        BARMM(0);
        // P6 (buf1, kh0, nh1) | stage B kh1(t1+1)
        DSB(1,0,1);
        if (more) STG_B(0,1,t1+1);
        BARMM(1);
        // P7 (buf1, kh1, nh0) | stage A kh0(t1+2) -> buf1 (kh0 freed at P6)
        DSA(1,1); DSB(1,1,0);
        if (more) STG_A(1,0,t1+2);
        BARMM(0);
        // P8 (buf1, kh1, nh1) | stage B kh0(t1+2); counted wait
        DSB(1,1,1);
        if (more) {
            STG_B(1,0,t1+2);
            asm volatile("s_waitcnt vmcnt(4)" ::: "memory");
        }
        BARMM(1);
    }

    // ---- epilogue via LDS: coalesced 16B stores, no write amplification ----
    if constexpr (sizeof(OutT) == 2) {
        const bool dorelu = RELUQK && (n0 < 1024);
        #pragma unroll
        for (int nf = 0; nf < 4; ++nf) {
            const int col = wn * 64 + nf * 16 + m;
            const float bval = bias[n0 + col];
            #pragma unroll
            for (int mt = 0; mt < 8; ++mt) {
                #pragma unroll
                for (int r = 0; r < 4; ++r) {
                    const int row = wm * 128 + mt * 16 + kc * 4 + r;
                    float c = acc[mt][nf][r] + bval;
                    if (dorelu) c = fmaxf(c, 0.f) * 0.17677669529663687f;  // 1/sqrt(32)
                    const int x = ((row >> 2) & 7) << 1;
                    lds[row * 256 + (((col >> 3) ^ x) << 3) + (col & 7)] = f2bf(c);
                }
            }
        }
        __syncthreads();
        #pragma unroll
        for (int it = 0; it < 16; ++it) {
            const int li = it * 512 + tid;
            const int row = li >> 5, ch = li & 31;
            const int x = ((row >> 2) & 7) << 1;
            bf16x8 v = *(const bf16x8*)&lds[row * 256 + ((ch ^ x) << 3)];
            *(bf16x8*)&C[(m0 + row) * (long)NCOLS + n0 + ch * 8] = v;
        }
    } else {
        float* ft = (float*)lds;                 // 128 rows x 256 f32 = 128 KiB/half
        #pragma unroll 1
        for (int half = 0; half < 2; ++half) {
            __syncthreads();
            if (wm == half) {
                #pragma unroll
                for (int nf = 0; nf < 4; ++nf) {
                    const int col = wn * 64 + nf * 16 + m;
                    const float bval = bias[n0 + col];
                    #pragma unroll
                    for (int mt = 0; mt < 8; ++mt) {
                        #pragma unroll
                        for (int r = 0; r < 4; ++r) {
                            const int row = mt * 16 + kc * 4 + r;   // 0..127
                            const int x = ((row >> 2) & 7) << 1;
                            ft[row * 256 + (((col >> 2) ^ x) << 2) + (col & 3)] =
                                acc[mt][nf][r] + bval;
                        }
                    }
                }
            }
            __syncthreads();
            #pragma unroll
            for (int it = 0; it < 16; ++it) {
                const int li = it * 512 + tid;
                const int row = li >> 6, ch = li & 63;
                const int x = ((row >> 2) & 7) << 1;
                float4 v = *(const float4*)&ft[row * 256 + ((ch ^ x) << 2)];
                *(float4*)&C[(m0 + half * 128 + row) * (long)NCOLS + n0 + ch * 4] = v;
            }
        }
    }
    #undef SUB
    #undef STG_A
    #undef STG_B
    #undef DSA
    #undef DSB
    #undef MM
    #undef BARMM
}

// ---------------------------------------------------------------- kv v4: 128-row chunks, f32 LDS tiles (no per-fma cvt)
// grid (bh=64, chunk=32). part_kv[bh][chunk][f][d], part_ks[bh][chunk][f].
__global__ __launch_bounds__(256) void kv_v3(const u16* __restrict__ Y,
                                             float* __restrict__ part_kv,
                                             float* __restrict__ part_ks)
{
    __shared__ float ksf[128 * 33];   // [n][f] f32, pad 33
    __shared__ float vsf[128 * 68];   // [n][d] f32, pad 68 (16B-aligned rows)
    const int bh = blockIdx.x, c = blockIdx.y;
    const int b = bh >> 4, h = bh & 15;
    const int tid = threadIdx.x;
    const long rbase = (long)b * 4096 + (long)c * 128;

    #pragma unroll
    for (int it = 0; it < 2; ++it) {
        const int lr = it * 64 + (tid >> 2), cc = (tid & 3) * 8;
        bf16x8 kx = *(const bf16x8*)(Y + (rbase + lr) * 2048 + 512 + h * 32 + cc);
        #pragma unroll
        for (int j = 0; j < 8; ++j) ksf[lr * 33 + cc + j] = bf2f((u16)kx[j]);
    }
    #pragma unroll
    for (int it = 0; it < 4; ++it) {
        const int lr = it * 32 + (tid >> 3), cc = (tid & 7) * 8;
        bf16x8 vx = *(const bf16x8*)(Y + (rbase + lr) * 2048 + 1024 + h * 64 + cc);
        #pragma unroll
        for (int j = 0; j < 8; ++j) vsf[lr * 68 + cc + j] = bf2f((u16)vx[j]);
    }
    __syncthreads();

    const int f = tid >> 3, dg = (tid & 7) * 8;
    float acc[8] = {};
    float ksacc = 0.f;
    #pragma unroll 4
    for (int n = 0; n < 128; ++n) {
        const float kf = ksf[n * 33 + f];
        const float4 v0 = *(const float4*)&vsf[n * 68 + dg];
        const float4 v1 = *(const float4*)&vsf[n * 68 + dg + 4];
        acc[0] += kf * v0.x; acc[1] += kf * v0.y;
        acc[2] += kf * v0.z; acc[3] += kf * v0.w;
        acc[4] += kf * v1.x; acc[5] += kf * v1.y;
        acc[6] += kf * v1.z; acc[7] += kf * v1.w;
        ksacc += kf;
    }

    float* o = part_kv + (((long)bh * 32 + c) * 32 + f) * 64 + dg;
    *(f32x4*)o       = f32x4{acc[0], acc[1], acc[2], acc[3]};
    *(f32x4*)(o + 4) = f32x4{acc[4], acc[5], acc[6], acc[7]};
    if ((tid & 7) == 0) part_ks[(bh * 32 + c) * 32 + f] = ksacc;
}

// reduce 32 partials -> kv[bh][f][d] (blocks 0..511) and ksum[bh][f] (512..519)
__global__ __launch_bounds__(256) void kv_reduce(const float* __restrict__ part_kv,
                                                 const float* __restrict__ part_ks,
                                                 float* __restrict__ kv,
                                                 float* __restrict__ ksum)
{
    const int idx = blockIdx.x * 256 + threadIdx.x;
    if (blockIdx.x < 512) {                       // 131072 kv elements
        const int bh = idx >> 11, off = idx & 2047;
        const float* p = part_kv + (long)bh * 65536 + off;
        float s = 0.f;
        #pragma unroll 8
        for (int c = 0; c < 32; c++) s += p[c * 2048];
        kv[idx] = s;
    } else {                                      // 2048 ksum elements
        const int i2 = idx - 512 * 256;
        const int bh = i2 >> 5, f = i2 & 31;
        const float* p = part_ks + bh * 1024 + f;
        float s = 0.f;
        #pragma unroll 8
        for (int c = 0; c < 32; c++) s += p[c * 32];
        ksum[i2] = s;
    }
}

// ---------------------------------------------------------------- attn v3: f32 LDS q-tile, kv in registers
__global__ __launch_bounds__(256) void attn_v2(const u16* __restrict__ Y,
                                               const float* __restrict__ kv,
                                               const float* __restrict__ ksum,
                                               u16* __restrict__ attn)
{
    __shared__ float qsf[64 * 36];    // [row][f] f32, pad 36 (16B-aligned rows)
    __shared__ float kss[32];
    __shared__ float zs[64];          // 1/(den+eps) per local row
    const int tid = threadIdx.x;
    const int bh = blockIdx.x;
    const int b = bh >> 4, h = bh & 15;
    const long row0 = (long)b * 4096 + (long)blockIdx.y * 64;

    {
        const int lr = tid >> 2, c8 = (tid & 3) * 8;
        bf16x8 qx = *(const bf16x8*)(Y + (row0 + lr) * 2048 + h * 32 + c8);
        #pragma unroll
        for (int j = 0; j < 8; ++j) qsf[lr * 36 + c8 + j] = bf2f((u16)qx[j]);
    }
    if (tid < 32) kss[tid] = ksum[bh * 32 + tid];

    const int wave = tid >> 6, lane = tid & 63;
    const float* kvg = kv + (long)bh * 2048 + lane;
    float kvreg[32];
    #pragma unroll
    for (int ff = 0; ff < 32; ++ff) kvreg[ff] = kvg[ff * 64];

    __syncthreads();

    {
        const int lr = wave * 16 + (lane & 15);
        float den = 0.f;
        #pragma unroll
        for (int fc = 0; fc < 8; ++fc) {
            const float4 q = *(const float4*)&qsf[lr * 36 + fc * 4];
            den += q.x * kss[fc * 4]     + q.y * kss[fc * 4 + 1]
                 + q.z * kss[fc * 4 + 2] + q.w * kss[fc * 4 + 3];
        }
        if (lane < 16) zs[lr] = 1.f / (den + 1e-8f);
    }
    __syncthreads();

    #pragma unroll
    for (int rg = 0; rg < 4; ++rg) {
        const int lr0 = wave * 16 + rg * 4;
        float acc0 = 0.f, acc1 = 0.f, acc2 = 0.f, acc3 = 0.f;
        #pragma unroll
        for (int fc = 0; fc < 8; ++fc) {
            const float4 q0 = *(const float4*)&qsf[(lr0 + 0) * 36 + fc * 4];
            const float4 q1 = *(const float4*)&qsf[(lr0 + 1) * 36 + fc * 4];
            const float4 q2 = *(const float4*)&qsf[(lr0 + 2) * 36 + fc * 4];
            const float4 q3 = *(const float4*)&qsf[(lr0 + 3) * 36 + fc * 4];
            const float k0 = kvreg[fc * 4], k1 = kvreg[fc * 4 + 1];
            const float k2 = kvreg[fc * 4 + 2], k3 = kvreg[fc * 4 + 3];
            acc0 += q0.x * k0 + q0.y * k1 + q0.z * k2 + q0.w * k3;
            acc1 += q1.x * k0 + q1.y * k1 + q1.z * k2 + q1.w * k3;
            acc2 += q2.x * k0 + q2.y * k1 + q2.z * k2 + q2.w * k3;
            acc3 += q3.x * k0 + q3.y * k1 + q3.z * k2 + q3.w * k3;
        }
        u16* op = attn + (row0 + lr0) * 1024 + h * 64 + lane;
        op[0]        = f2bf(acc0 * zs[lr0 + 0]);
        op[1024]     = f2bf(acc1 * zs[lr0 + 1]);
        op[2 * 1024] = f2bf(acc2 * zs[lr0 + 2]);
        op[3 * 1024] = f2bf(acc3 * zs[lr0 + 3]);
    }
}

// ---------------------------------------------------------------- launch
extern "C" void kernel_launch(void* const* d_in, const int* in_sizes, int n_in,
                              void* d_out, int out_size, void* d_ws, size_t ws_size,
                              hipStream_t stream)
{
    const float* x    = (const float*)d_in[0];
    const float* Wq   = (const float*)d_in[1];
    const float* bq   = (const float*)d_in[2];
    const float* Wk   = (const float*)d_in[3];
    const float* bk   = (const float*)d_in[4];
    const float* Wv   = (const float*)d_in[5];
    const float* bv   = (const float*)d_in[6];
    const float* proj = (const float*)d_in[7];
    const float* Wo   = (const float*)d_in[8];
    const float* bo   = (const float*)d_in[9];

    // Region w+0 (33.5 MB) is time-multiplexed: xbf (dies at gemm_qkv) ->
    // part_kv (kv_v3..kv_reduce, 16.8 MB) -> attn (attn_v2..gemm_out).
    char* w = (char*)d_ws;
    u16*   xbf     = (u16*)  (w);                  // 33,554,432 B
    float* part_kv = (float*)(w);                  // alias (16,777,216 B used)
    u16*   attn    = (u16*)  (w);                  // alias
    u16*   wallT   = (u16*)  (w + 33554432);       //  4,194,304 B
    u16*   woT     = (u16*)  (w + 37748736);       //  2,097,152 B
    float* bias    = (float*)(w + 39845888);       //      8,192 B
    float* kv      = (float*)(w + 39854080);       //    524,288 B
    float* ksum    = (float*)(w + 40378368);       //      8,192 B
    u16*   Y       = (u16*)  (w + 40386560);       // 67,108,864 B
    float* part_ks = (float*)(w + 107495424);      //    262,144 B used

    cast_x<<<8192, 256, 0, stream>>>((const float4*)x, (bf16x8*)xbf);

    fold_qk<<<256, 256, 0, stream>>>(Wq, Wk, bq, bk, proj, wallT, bias);

    transpose_vo<<<512, 256, 0, stream>>>(Wv, Wo, bv, wallT, woT, bias);

    gemm256<8, true, u16><<<512, 512, 0, stream>>>(xbf, wallT, bias, Y);

    kv_v3<<<dim3(64, 32), 256, 0, stream>>>(Y, part_kv, part_ks);

    kv_reduce<<<520, 256, 0, stream>>>(part_kv, part_ks, kv, ksum);

    attn_v2<<<dim3(64, 64), 256, 0, stream>>>(Y, kv, ksum, attn);

    gemm256<4, false, float><<<256, 512, 0, stream>>>(attn, woT, bo, (float*)d_out);
}

// Round 6
// 315.567 us; speedup vs baseline: 1.3710x; 1.0093x over previous
//
#include <hip/hip_runtime.h>

typedef unsigned short u16;
typedef __attribute__((ext_vector_type(8))) short bf16x8;
typedef __attribute__((ext_vector_type(4))) float f32x4;

__device__ inline float bf2f(u16 u) {
    unsigned v = ((unsigned)u) << 16;
    return __builtin_bit_cast(float, v);
}
__device__ inline u16 f2bf(float f) {
    unsigned u = __builtin_bit_cast(unsigned, f);
    u += 0x7fff + ((u >> 16) & 1);   // RNE
    return (u16)(u >> 16);
}

// async global->LDS, 16B per lane. LDS dest = wave-uniform base + lane*16.
__device__ inline void gload_lds16(const void* g, void* l) {
    __builtin_amdgcn_global_load_lds(
        (const __attribute__((address_space(1))) unsigned int*)(unsigned long long)g,
        (__attribute__((address_space(3))) unsigned int*)(unsigned)(unsigned long long)l,
        16, 0, 0);
}

// ---------------------------------------------------------------- prep: cast_x + fold_qk + transpose_vo fused
// bid < 8192:      cast x -> bf16 (8 floats/thread)
// bid 8192..8447:  Wq/Wk fold via LDS panel (coalesced reads)
// bid 8448..8959:  Wv/Wo 64x64 LDS tile-transpose
__global__ __launch_bounds__(256) void prep(
    const float4* __restrict__ x, bf16x8* __restrict__ xb,
    const float* __restrict__ Wq, const float* __restrict__ Wk,
    const float* __restrict__ bq, const float* __restrict__ bk,
    const float* __restrict__ proj,
    const float* __restrict__ Wv, const float* __restrict__ Wo,
    const float* __restrict__ bv,
    u16* __restrict__ WallT, u16* __restrict__ WoT, float* __restrict__ bias_all)
{
    __shared__ float smem[10240];   // 40 KB union
    const int bid = blockIdx.x;
    const int tid = threadIdx.x;

    if (bid < 8192) {
        // -------- cast_x --------
        long i = (long)bid * 256 + tid;
        float4 v0 = x[2 * i];
        float4 v1 = x[2 * i + 1];
        bf16x8 o;
        o[0] = (short)f2bf(v0.x); o[1] = (short)f2bf(v0.y);
        o[2] = (short)f2bf(v0.z); o[3] = (short)f2bf(v0.w);
        o[4] = (short)f2bf(v1.x); o[5] = (short)f2bf(v1.y);
        o[6] = (short)f2bf(v1.z); o[7] = (short)f2bf(v1.w);
        xb[i] = o;
    } else if (bid < 8448) {
        // -------- fold_qk --------
        const int fb = bid - 8192;
        const int qk = fb >> 7, h = (fb >> 3) & 15, kt = fb & 7;
        const float* W  = qk ? Wk : Wq;
        const float* bb = qk ? bk : bq;
        const int kin0 = kt * 128;
        float* pj    = smem;          // proj[d][f], 2048 floats
        float* panel = smem + 2048;   // W[kin][d] panel, 8192 floats
        {
            const float4* ps = (const float4*)proj;
            float4* pd = (float4*)pj;
            #pragma unroll
            for (int it = 0; it < 2; ++it) pd[it * 256 + tid] = ps[it * 256 + tid];
        }
        #pragma unroll
        for (int it = 0; it < 8; ++it) {
            const int li = it * 256 + tid;            // 2048 float4s
            const int row = li >> 4, c4 = (li & 15) * 4;
            *(float4*)&panel[row * 64 + c4] =
                *(const float4*)&W[(long)(kin0 + row) * 1024 + h * 64 + c4];
        }
        __syncthreads();

        const int f = tid & 31, g = tid >> 5;        // 8 groups x 16 kin rows
        float pjr[64];
        #pragma unroll
        for (int d = 0; d < 64; ++d) pjr[d] = pj[d * 32 + f];

        alignas(16) u16 outv[16];
        #pragma unroll
        for (int rr = 0; rr < 16; ++rr) {
            const float4* prow = (const float4*)&panel[(g * 16 + rr) * 64];
            float acc = 0.f;
            #pragma unroll
            for (int d4 = 0; d4 < 16; ++d4) {
                float4 p = prow[d4];
                acc += p.x * pjr[d4 * 4]     + p.y * pjr[d4 * 4 + 1]
                     + p.z * pjr[d4 * 4 + 2] + p.w * pjr[d4 * 4 + 3];
            }
            outv[rr] = f2bf(acc);
        }
        u16* dst = WallT + (long)(qk * 512 + h * 32 + f) * 1024 + kin0 + g * 16;
        *(bf16x8*)dst     = *(const bf16x8*)&outv[0];
        *(bf16x8*)&dst[8] = *(const bf16x8*)&outv[8];

        if (kt == 0 && g == 0) {
            float a = 0.f;
            #pragma unroll
            for (int d = 0; d < 64; ++d) a += bb[h * 64 + d] * pjr[d];
            bias_all[qk * 512 + h * 32 + f] = a;
        }
    } else {
        // -------- transpose_vo --------
        const int tb = bid - 8448;
        const bool isV = (tb < 256);
        const int tile = isV ? tb : (tb - 256);
        const int kt = tile >> 4, ct = tile & 15;     // 16x16 tiles of 64x64
        const float* src = isV ? Wv : Wo;
        float* T = smem;                              // [64][65]
        #pragma unroll
        for (int it = 0; it < 16; ++it) {
            const int kl = it * 4 + (tid >> 6);
            T[kl * 65 + (tid & 63)] = src[(long)(kt * 64 + kl) * 1024 + ct * 64 + (tid & 63)];
        }
        __syncthreads();
        #pragma unroll
        for (int it = 0; it < 2; ++it) {
            const int li = it * 256 + tid;
            const int cl = li >> 3, k8 = (li & 7) * 8;
            bf16x8 o;
            #pragma unroll
            for (int j = 0; j < 8; ++j) o[j] = (short)f2bf(T[(k8 + j) * 65 + cl]);
            u16* dst = isV ? (WallT + (long)(1024 + ct * 64 + cl) * 1024)
                           : (WoT   + (long)(ct * 64 + cl) * 1024);
            *(bf16x8*)&dst[kt * 64 + k8] = o;
        }
        if (isV && kt == 0 && tid < 64) bias_all[1024 + ct * 64 + tid] = bv[ct * 64 + tid];
    }
}

// ---------------------------------------------------------------- 256x256 8-phase pipelined bf16 MFMA GEMM
// K=1024 fixed. B transposed [N][K]. 512 threads = 8 waves (2m x 4n), per-wave
// output 128x64 (8 m-frags x 4 n-frags of 16x16x32 MFMA).
// LDS 128KiB: [buf(2)][khalf(2)][A/B(2)] subtiles of 256 rows x 32 u16 (chunk-XOR
// swizzle: pre-swizzled global source, linear gload_lds dest, (kc^sel) read).
// Schedule: 8 phases / 2 K-tiles, counted vmcnt(4) at phases 4 & 8, raw s_barrier,
// setprio around MFMA. Epilogue: C tile staged in LDS (swizzled), coalesced 16B.
// moff: row offset (kernel split into row-range dispatches for profiling grain).
template<int NBN, bool RELUQK, typename OutT>
__global__ __launch_bounds__(512, 2) void gemm256(
    const u16* __restrict__ A, const u16* __restrict__ Bt,
    const float* __restrict__ bias, OutT* __restrict__ C, long moff)
{
    constexpr int NCOLS = NBN * 256;
    __shared__ alignas(16) u16 lds[65536];   // 131072 B

    // XCD-bijective swizzle (gridDim.x % 8 == 0), n-fastest inside a chunk.
    const int bid = blockIdx.x;
    const int wg  = (bid & 7) * ((int)gridDim.x >> 3) + (bid >> 3);
    const long m0 = moff + (long)(wg / NBN) * 256;
    const long n0 = (long)(wg % NBN) * 256;

    const int tid  = threadIdx.x;
    const int wave = tid >> 6, lane = tid & 63;
    const int wm = wave >> 2, wn = wave & 3;

    // ---- staging addresses (per thread, 2 loads per half-tile) ----
    const int srow = wave * 32 + (lane >> 2);                 // rows srow, srow+16
    const int gch  = ((lane & 3) ^ ((lane >> 3) & 3)) * 8;    // pre-swizzled k-chunk
    const u16* pA0 = A  + (m0 + srow) * 1024 + gch;
    const u16* pA1 = pA0 + 16 * 1024;
    const u16* pB0 = Bt + (n0 + srow) * 1024 + gch;
    const u16* pB1 = pB0 + 16 * 1024;

    #define SUB(b_,kh_,ab_) (lds + (((b_)*2+(kh_))*2+(ab_))*8192)
    #define STG_A(b_,kh_,t_) { const int k0_ = (t_)*64 + (kh_)*32;            \
        u16* d_ = SUB(b_,kh_,0) + wave * 1024;                                \
        gload_lds16(pA0 + k0_, d_); gload_lds16(pA1 + k0_, d_ + 512); }
    #define STG_B(b_,kh_,t_) { const int k0_ = (t_)*64 + (kh_)*32;            \
        u16* d_ = SUB(b_,kh_,1) + wave * 1024;                                \
        gload_lds16(pB0 + k0_, d_); gload_lds16(pB1 + k0_, d_ + 512); }

    // ---- fragment read addresses ----
    const int m  = lane & 15, kc = lane >> 4;
    const int off  = (kc ^ ((m >> 1) & 3)) * 8;               // de-swizzle
    const int arow = (wm * 128 + m) * 32 + off;               // + mt*512
    const int brow = (wn * 64  + m) * 32 + off;               // + nh*1024 + j*512

    f32x4  acc[8][4] = {};
    bf16x8 af[8];
    bf16x8 b0, b1;

    #define DSA(b_,kh_) { const u16* s_ = SUB(b_,kh_,0);                      \
        _Pragma("unroll") for (int mt_ = 0; mt_ < 8; ++mt_)                   \
            af[mt_] = *(const bf16x8*)(s_ + arow + mt_ * 512); }
    #define DSB(b_,kh_,nh_) { const u16* s_ = SUB(b_,kh_,1) + brow + (nh_)*1024; \
        b0 = *(const bf16x8*)(s_); b1 = *(const bf16x8*)(s_ + 512); }
    #define MM(nh_) { _Pragma("unroll") for (int mt_ = 0; mt_ < 8; ++mt_) {   \
        acc[mt_][(nh_)*2]   = __builtin_amdgcn_mfma_f32_16x16x32_bf16(        \
            af[mt_], b0, acc[mt_][(nh_)*2],   0, 0, 0);                       \
        acc[mt_][(nh_)*2+1] = __builtin_amdgcn_mfma_f32_16x16x32_bf16(        \
            af[mt_], b1, acc[mt_][(nh_)*2+1], 0, 0, 0); } }
    #define BARMM(nh_)                                                        \
        __builtin_amdgcn_s_barrier();                                         \
        asm volatile("s_waitcnt lgkmcnt(0)" ::: "memory");                    \
        __builtin_amdgcn_s_setprio(1);                                        \
        MM(nh_);                                                              \
        __builtin_amdgcn_s_setprio(0);                                        \
        __builtin_amdgcn_s_barrier();

    // ---- prologue: tile0 (both k-halves) + tile1 k-half0; allow last 4 in flight
    STG_A(0,0,0); STG_B(0,0,0);
    STG_A(0,1,0); STG_B(0,1,0);
    STG_A(1,0,1); STG_B(1,0,1);
    asm volatile("s_waitcnt vmcnt(4)" ::: "memory");
    __builtin_amdgcn_s_barrier();

    // ---- main loop: 8 iterations x 2 K-tiles (tile 2i in buf0, 2i+1 in buf1)
    #pragma unroll 1
    for (int i = 0; i < 8; ++i) {
        const int  t1   = 2 * i + 1;
        const bool more = (i < 7);
        // P1 (buf0, kh0, nh0) | stage A kh1(t1) -> buf1
        DSA(0,0); DSB(0,0,0);
        STG_A(1,1,t1);
        BARMM(0);
        // P2 (buf0, kh0, nh1) | stage B kh1(t1)
        DSB(0,0,1);
        STG_B(1,1,t1);
        BARMM(1);
        // P3 (buf0, kh1, nh0) | stage A kh0(t1+1) -> buf0 (kh0 freed at P2)
        DSA(0,1); DSB(0,1,0);
        if (more) STG_A(0,0,t1+1);
        BARMM(0);
        // P4 (buf0, kh1, nh1) | stage B kh0(t1+1); counted wait
        DSB(0,1,1);
        if (more) {
            STG_B(0,0,t1+1);
            asm volatile("s_waitcnt vmcnt(4)" ::: "memory");
        } else {
            asm volatile("s_waitcnt vmcnt(0)" ::: "memory");
        }
        BARMM(1);
        // P5 (buf1, kh0, nh0) | stage A kh1(t1+1) -> buf0 (kh1 freed at P4)
        DSA(1,0); DSB(1,0,0);
        if (more) STG_A(0,1,t1+1);
        BARMM(0);
        // P6 (buf1, kh0, nh1) | stage B kh1(t1+1)
        DSB(1,0,1);
        if (more) STG_B(0,1,t1+1);
        BARMM(1);
        // P7 (buf1, kh1, nh0) | stage A kh0(t1+2) -> buf1 (kh0 freed at P6)
        DSA(1,1); DSB(1,1,0);
        if (more) STG_A(1,0,t1+2);
        BARMM(0);
        // P8 (buf1, kh1, nh1) | stage B kh0(t1+2); counted wait
        DSB(1,1,1);
        if (more) {
            STG_B(1,0,t1+2);
            asm volatile("s_waitcnt vmcnt(4)" ::: "memory");
        }
        BARMM(1);
    }

    // ---- epilogue via LDS: coalesced 16B stores, no write amplification ----
    if constexpr (sizeof(OutT) == 2) {
        const bool dorelu = RELUQK && (n0 < 1024);
        #pragma unroll
        for (int nf = 0; nf < 4; ++nf) {
            const int col = wn * 64 + nf * 16 + m;
            const float bval = bias[n0 + col];
            #pragma unroll
            for (int mt = 0; mt < 8; ++mt) {
                #pragma unroll
                for (int r = 0; r < 4; ++r) {
                    const int row = wm * 128 + mt * 16 + kc * 4 + r;
                    float c = acc[mt][nf][r] + bval;
                    if (dorelu) c = fmaxf(c, 0.f) * 0.17677669529663687f;  // 1/sqrt(32)
                    const int x = ((row >> 2) & 7) << 1;
                    lds[row * 256 + (((col >> 3) ^ x) << 3) + (col & 7)] = f2bf(c);
                }
            }
        }
        __syncthreads();
        #pragma unroll
        for (int it = 0; it < 16; ++it) {
            const int li = it * 512 + tid;
            const int row = li >> 5, ch = li & 31;
            const int x = ((row >> 2) & 7) << 1;
            bf16x8 v = *(const bf16x8*)&lds[row * 256 + ((ch ^ x) << 3)];
            *(bf16x8*)&C[(m0 + row) * (long)NCOLS + n0 + ch * 8] = v;
        }
    } else {
        float* ft = (float*)lds;                 // 128 rows x 256 f32 = 128 KiB/half
        #pragma unroll 1
        for (int half = 0; half < 2; ++half) {
            __syncthreads();
            if (wm == half) {
                #pragma unroll
                for (int nf = 0; nf < 4; ++nf) {
                    const int col = wn * 64 + nf * 16 + m;
                    const float bval = bias[n0 + col];
                    #pragma unroll
                    for (int mt = 0; mt < 8; ++mt) {
                        #pragma unroll
                        for (int r = 0; r < 4; ++r) {
                            const int row = mt * 16 + kc * 4 + r;   // 0..127
                            const int x = ((row >> 2) & 7) << 1;
                            ft[row * 256 + (((col >> 2) ^ x) << 2) + (col & 3)] =
                                acc[mt][nf][r] + bval;
                        }
                    }
                }
            }
            __syncthreads();
            #pragma unroll
            for (int it = 0; it < 16; ++it) {
                const int li = it * 512 + tid;
                const int row = li >> 6, ch = li & 63;
                const int x = ((row >> 2) & 7) << 1;
                float4 v = *(const float4*)&ft[row * 256 + ((ch ^ x) << 2)];
                *(float4*)&C[(m0 + half * 128 + row) * (long)NCOLS + n0 + ch * 4] = v;
            }
        }
    }
    #undef SUB
    #undef STG_A
    #undef STG_B
    #undef DSA
    #undef DSB
    #undef MM
    #undef BARMM
}

// ---------------------------------------------------------------- kv v4: 128-row chunks, f32 LDS tiles (no per-fma cvt)
// grid (bh=64, chunk=32). part_kv[bh][chunk][f][d], part_ks[bh][chunk][f].
__global__ __launch_bounds__(256) void kv_v3(const u16* __restrict__ Y,
                                             float* __restrict__ part_kv,
                                             float* __restrict__ part_ks)
{
    __shared__ float ksf[128 * 33];   // [n][f] f32, pad 33
    __shared__ float vsf[128 * 68];   // [n][d] f32, pad 68 (16B-aligned rows)
    const int bh = blockIdx.x, c = blockIdx.y;
    const int b = bh >> 4, h = bh & 15;
    const int tid = threadIdx.x;
    const long rbase = (long)b * 4096 + (long)c * 128;

    #pragma unroll
    for (int it = 0; it < 2; ++it) {
        const int lr = it * 64 + (tid >> 2), cc = (tid & 3) * 8;
        bf16x8 kx = *(const bf16x8*)(Y + (rbase + lr) * 2048 + 512 + h * 32 + cc);
        #pragma unroll
        for (int j = 0; j < 8; ++j) ksf[lr * 33 + cc + j] = bf2f((u16)kx[j]);
    }
    #pragma unroll
    for (int it = 0; it < 4; ++it) {
        const int lr = it * 32 + (tid >> 3), cc = (tid & 7) * 8;
        bf16x8 vx = *(const bf16x8*)(Y + (rbase + lr) * 2048 + 1024 + h * 64 + cc);
        #pragma unroll
        for (int j = 0; j < 8; ++j) vsf[lr * 68 + cc + j] = bf2f((u16)vx[j]);
    }
    __syncthreads();

    const int f = tid >> 3, dg = (tid & 7) * 8;
    float acc[8] = {};
    float ksacc = 0.f;
    #pragma unroll 4
    for (int n = 0; n < 128; ++n) {
        const float kf = ksf[n * 33 + f];
        const float4 v0 = *(const float4*)&vsf[n * 68 + dg];
        const float4 v1 = *(const float4*)&vsf[n * 68 + dg + 4];
        acc[0] += kf * v0.x; acc[1] += kf * v0.y;
        acc[2] += kf * v0.z; acc[3] += kf * v0.w;
        acc[4] += kf * v1.x; acc[5] += kf * v1.y;
        acc[6] += kf * v1.z; acc[7] += kf * v1.w;
        ksacc += kf;
    }

    float* o = part_kv + (((long)bh * 32 + c) * 32 + f) * 64 + dg;
    *(f32x4*)o       = f32x4{acc[0], acc[1], acc[2], acc[3]};
    *(f32x4*)(o + 4) = f32x4{acc[4], acc[5], acc[6], acc[7]};
    if ((tid & 7) == 0) part_ks[(bh * 32 + c) * 32 + f] = ksacc;
}

// reduce 32 partials -> kv[bh][f][d] (blocks 0..511) and ksum[bh][f] (512..519)
__global__ __launch_bounds__(256) void kv_reduce(const float* __restrict__ part_kv,
                                                 const float* __restrict__ part_ks,
                                                 float* __restrict__ kv,
                                                 float* __restrict__ ksum)
{
    const int idx = blockIdx.x * 256 + threadIdx.x;
    if (blockIdx.x < 512) {                       // 131072 kv elements
        const int bh = idx >> 11, off = idx & 2047;
        const float* p = part_kv + (long)bh * 65536 + off;
        float s = 0.f;
        #pragma unroll 8
        for (int c = 0; c < 32; c++) s += p[c * 2048];
        kv[idx] = s;
    } else {                                      // 2048 ksum elements
        const int i2 = idx - 512 * 256;
        const int bh = i2 >> 5, f = i2 & 31;
        const float* p = part_ks + bh * 1024 + f;
        float s = 0.f;
        #pragma unroll 8
        for (int c = 0; c < 32; c++) s += p[c * 32];
        ksum[i2] = s;
    }
}

// ---------------------------------------------------------------- attn v3: f32 LDS q-tile, kv in registers
__global__ __launch_bounds__(256) void attn_v2(const u16* __restrict__ Y,
                                               const float* __restrict__ kv,
                                               const float* __restrict__ ksum,
                                               u16* __restrict__ attn)
{
    __shared__ float qsf[64 * 36];    // [row][f] f32, pad 36 (16B-aligned rows)
    __shared__ float kss[32];
    __shared__ float zs[64];          // 1/(den+eps) per local row
    const int tid = threadIdx.x;
    const int bh = blockIdx.x;
    const int b = bh >> 4, h = bh & 15;
    const long row0 = (long)b * 4096 + (long)blockIdx.y * 64;

    {
        const int lr = tid >> 2, c8 = (tid & 3) * 8;
        bf16x8 qx = *(const bf16x8*)(Y + (row0 + lr) * 2048 + h * 32 + c8);
        #pragma unroll
        for (int j = 0; j < 8; ++j) qsf[lr * 36 + c8 + j] = bf2f((u16)qx[j]);
    }
    if (tid < 32) kss[tid] = ksum[bh * 32 + tid];

    const int wave = tid >> 6, lane = tid & 63;
    const float* kvg = kv + (long)bh * 2048 + lane;
    float kvreg[32];
    #pragma unroll
    for (int ff = 0; ff < 32; ++ff) kvreg[ff] = kvg[ff * 64];

    __syncthreads();

    {
        const int lr = wave * 16 + (lane & 15);
        float den = 0.f;
        #pragma unroll
        for (int fc = 0; fc < 8; ++fc) {
            const float4 q = *(const float4*)&qsf[lr * 36 + fc * 4];
            den += q.x * kss[fc * 4]     + q.y * kss[fc * 4 + 1]
                 + q.z * kss[fc * 4 + 2] + q.w * kss[fc * 4 + 3];
        }
        if (lane < 16) zs[lr] = 1.f / (den + 1e-8f);
    }
    __syncthreads();

    #pragma unroll
    for (int rg = 0; rg < 4; ++rg) {
        const int lr0 = wave * 16 + rg * 4;
        float acc0 = 0.f, acc1 = 0.f, acc2 = 0.f, acc3 = 0.f;
        #pragma unroll
        for (int fc = 0; fc < 8; ++fc) {
            const float4 q0 = *(const float4*)&qsf[(lr0 + 0) * 36 + fc * 4];
            const float4 q1 = *(const float4*)&qsf[(lr0 + 1) * 36 + fc * 4];
            const float4 q2 = *(const float4*)&qsf[(lr0 + 2) * 36 + fc * 4];
            const float4 q3 = *(const float4*)&qsf[(lr0 + 3) * 36 + fc * 4];
            const float k0 = kvreg[fc * 4], k1 = kvreg[fc * 4 + 1];
            const float k2 = kvreg[fc * 4 + 2], k3 = kvreg[fc * 4 + 3];
            acc0 += q0.x * k0 + q0.y * k1 + q0.z * k2 + q0.w * k3;
            acc1 += q1.x * k0 + q1.y * k1 + q1.z * k2 + q1.w * k3;
            acc2 += q2.x * k0 + q2.y * k1 + q2.z * k2 + q2.w * k3;
            acc3 += q3.x * k0 + q3.y * k1 + q3.z * k2 + q3.w * k3;
        }
        u16* op = attn + (row0 + lr0) * 1024 + h * 64 + lane;
        op[0]        = f2bf(acc0 * zs[lr0 + 0]);
        op[1024]     = f2bf(acc1 * zs[lr0 + 1]);
        op[2 * 1024] = f2bf(acc2 * zs[lr0 + 2]);
        op[3 * 1024] = f2bf(acc3 * zs[lr0 + 3]);
    }
}

// ---------------------------------------------------------------- launch
extern "C" void kernel_launch(void* const* d_in, const int* in_sizes, int n_in,
                              void* d_out, int out_size, void* d_ws, size_t ws_size,
                              hipStream_t stream)
{
    const float* x    = (const float*)d_in[0];
    const float* Wq   = (const float*)d_in[1];
    const float* bq   = (const float*)d_in[2];
    const float* Wk   = (const float*)d_in[3];
    const float* bk   = (const float*)d_in[4];
    const float* Wv   = (const float*)d_in[5];
    const float* bv   = (const float*)d_in[6];
    const float* proj = (const float*)d_in[7];
    const float* Wo   = (const float*)d_in[8];
    const float* bo   = (const float*)d_in[9];

    // Region w+0 (33.5 MB) is time-multiplexed: xbf (dies at gemm_qkv) ->
    // part_kv (kv_v3..kv_reduce, 16.8 MB) -> attn (attn_v2..gemm_out).
    char* w = (char*)d_ws;
    u16*   xbf     = (u16*)  (w);                  // 33,554,432 B
    float* part_kv = (float*)(w);                  // alias (16,777,216 B used)
    u16*   attn    = (u16*)  (w);                  // alias
    u16*   wallT   = (u16*)  (w + 33554432);       //  4,194,304 B
    u16*   woT     = (u16*)  (w + 37748736);       //  2,097,152 B
    float* bias    = (float*)(w + 39845888);       //      8,192 B
    float* kv      = (float*)(w + 39854080);       //    524,288 B
    float* ksum    = (float*)(w + 40378368);       //      8,192 B
    u16*   Y       = (u16*)  (w + 40386560);       // 67,108,864 B
    float* part_ks = (float*)(w + 107495424);      //    262,144 B used

    prep<<<8960, 256, 0, stream>>>((const float4*)x, (bf16x8*)xbf,
                                   Wq, Wk, bq, bk, proj, Wv, Wo, bv,
                                   wallT, woT, bias);

    gemm256<8, true, u16><<<256, 512, 0, stream>>>(xbf, wallT, bias, Y, 0L);
    gemm256<8, true, u16><<<256, 512, 0, stream>>>(xbf, wallT, bias, Y, 8192L);

    kv_v3<<<dim3(64, 32), 256, 0, stream>>>(Y, part_kv, part_ks);

    kv_reduce<<<520, 256, 0, stream>>>(part_kv, part_ks, kv, ksum);

    attn_v2<<<dim3(64, 64), 256, 0, stream>>>(Y, kv, ksum, attn);

    gemm256<4, false, float><<<256, 512, 0, stream>>>(attn, woT, bo, (float*)d_out, 0L);
}

// Round 7
// 308.254 us; speedup vs baseline: 1.4035x; 1.0237x over previous
//
#include <hip/hip_runtime.h>

typedef unsigned short u16;
typedef __attribute__((ext_vector_type(8))) short bf16x8;
typedef __attribute__((ext_vector_type(4))) float f32x4;

__device__ inline float bf2f(u16 u) {
    unsigned v = ((unsigned)u) << 16;
    return __builtin_bit_cast(float, v);
}
__device__ inline u16 f2bf(float f) {
    unsigned u = __builtin_bit_cast(unsigned, f);
    u += 0x7fff + ((u >> 16) & 1);   // RNE
    return (u16)(u >> 16);
}

// async global->LDS, 16B per lane. LDS dest = wave-uniform base + lane*16.
__device__ inline void gload_lds16(const void* g, void* l) {
    __builtin_amdgcn_global_load_lds(
        (const __attribute__((address_space(1))) unsigned int*)(unsigned long long)g,
        (__attribute__((address_space(3))) unsigned int*)(unsigned)(unsigned long long)l,
        16, 0, 0);
}

// ---------------------------------------------------------------- prep: cast_x + fold_qk + transpose_v fused
// bid < 8192:      cast x -> bf16 (8 floats/thread)
// bid 8192..8447:  Wq/Wk fold via LDS panel (coalesced reads)
// bid 8448..8703:  Wv 64x64 LDS tile-transpose -> WallT rows 1024..2047
__global__ __launch_bounds__(256) void prep(
    const float4* __restrict__ x, bf16x8* __restrict__ xb,
    const float* __restrict__ Wq, const float* __restrict__ Wk,
    const float* __restrict__ bq, const float* __restrict__ bk,
    const float* __restrict__ proj,
    const float* __restrict__ Wv, const float* __restrict__ bv,
    u16* __restrict__ WallT, float* __restrict__ bias_all)
{
    __shared__ float smem[10240];   // 40 KB union
    const int bid = blockIdx.x;
    const int tid = threadIdx.x;

    if (bid < 8192) {
        // -------- cast_x --------
        long i = (long)bid * 256 + tid;
        float4 v0 = x[2 * i];
        float4 v1 = x[2 * i + 1];
        bf16x8 o;
        o[0] = (short)f2bf(v0.x); o[1] = (short)f2bf(v0.y);
        o[2] = (short)f2bf(v0.z); o[3] = (short)f2bf(v0.w);
        o[4] = (short)f2bf(v1.x); o[5] = (short)f2bf(v1.y);
        o[6] = (short)f2bf(v1.z); o[7] = (short)f2bf(v1.w);
        xb[i] = o;
    } else if (bid < 8448) {
        // -------- fold_qk --------
        const int fb = bid - 8192;
        const int qk = fb >> 7, h = (fb >> 3) & 15, kt = fb & 7;
        const float* W  = qk ? Wk : Wq;
        const float* bb = qk ? bk : bq;
        const int kin0 = kt * 128;
        float* pj    = smem;          // proj[d][f], 2048 floats
        float* panel = smem + 2048;   // W[kin][d] panel, 8192 floats
        {
            const float4* ps = (const float4*)proj;
            float4* pd = (float4*)pj;
            #pragma unroll
            for (int it = 0; it < 2; ++it) pd[it * 256 + tid] = ps[it * 256 + tid];
        }
        #pragma unroll
        for (int it = 0; it < 8; ++it) {
            const int li = it * 256 + tid;            // 2048 float4s
            const int row = li >> 4, c4 = (li & 15) * 4;
            *(float4*)&panel[row * 64 + c4] =
                *(const float4*)&W[(long)(kin0 + row) * 1024 + h * 64 + c4];
        }
        __syncthreads();

        const int f = tid & 31, g = tid >> 5;        // 8 groups x 16 kin rows
        float pjr[64];
        #pragma unroll
        for (int d = 0; d < 64; ++d) pjr[d] = pj[d * 32 + f];

        alignas(16) u16 outv[16];
        #pragma unroll
        for (int rr = 0; rr < 16; ++rr) {
            const float4* prow = (const float4*)&panel[(g * 16 + rr) * 64];
            float acc = 0.f;
            #pragma unroll
            for (int d4 = 0; d4 < 16; ++d4) {
                float4 p = prow[d4];
                acc += p.x * pjr[d4 * 4]     + p.y * pjr[d4 * 4 + 1]
                     + p.z * pjr[d4 * 4 + 2] + p.w * pjr[d4 * 4 + 3];
            }
            outv[rr] = f2bf(acc);
        }
        u16* dst = WallT + (long)(qk * 512 + h * 32 + f) * 1024 + kin0 + g * 16;
        *(bf16x8*)dst     = *(const bf16x8*)&outv[0];
        *(bf16x8*)&dst[8] = *(const bf16x8*)&outv[8];

        if (kt == 0 && g == 0) {
            float a = 0.f;
            #pragma unroll
            for (int d = 0; d < 64; ++d) a += bb[h * 64 + d] * pjr[d];
            bias_all[qk * 512 + h * 32 + f] = a;
        }
    } else {
        // -------- transpose_v --------
        const int tile = bid - 8448;
        const int kt = tile >> 4, ct = tile & 15;     // 16x16 tiles of 64x64
        float* T = smem;                              // [64][65]
        #pragma unroll
        for (int it = 0; it < 16; ++it) {
            const int kl = it * 4 + (tid >> 6);
            T[kl * 65 + (tid & 63)] = Wv[(long)(kt * 64 + kl) * 1024 + ct * 64 + (tid & 63)];
        }
        __syncthreads();
        #pragma unroll
        for (int it = 0; it < 2; ++it) {
            const int li = it * 256 + tid;
            const int cl = li >> 3, k8 = (li & 7) * 8;
            bf16x8 o;
            #pragma unroll
            for (int j = 0; j < 8; ++j) o[j] = (short)f2bf(T[(k8 + j) * 65 + cl]);
            u16* dst = WallT + (long)(1024 + ct * 64 + cl) * 1024;
            *(bf16x8*)&dst[kt * 64 + k8] = o;
        }
        if (kt == 0 && tid < 64) bias_all[1024 + ct * 64 + tid] = bv[ct * 64 + tid];
    }
}

// ---------------------------------------------------------------- 256x256 8-phase pipelined bf16 MFMA GEMM
// KDIM in {512,1024}. B transposed [N][KDIM]. 512 threads = 8 waves (2m x 4n),
// per-wave output 128x64 (8 m-frags x 4 n-frags of 16x16x32 MFMA).
// LDS 128KiB: [buf(2)][khalf(2)][A/B(2)] subtiles of 256 rows x 32 u16 (chunk-XOR
// swizzle: pre-swizzled global source, linear gload_lds dest, (kc^sel) read).
// Schedule: 8 phases / 2 K-tiles, counted vmcnt(4) at phases 4 & 8, raw s_barrier,
// setprio around MFMA. Epilogue: C tile staged in LDS (swizzled), coalesced 16B.
// PERBATCH: B matrix is per-batch (batch = m0>>12, B stride 1024*KDIM).
template<int NBN, bool RELUQK, typename OutT, int KDIM, bool PERBATCH>
__global__ __launch_bounds__(512, 2) void gemm256(
    const u16* __restrict__ A, const u16* __restrict__ Bt,
    const float* __restrict__ bias, OutT* __restrict__ C)
{
    constexpr int NWG   = 64 * NBN;
    constexpr int NCOLS = NBN * 256;
    constexpr int ITERS = KDIM / 128;
    __shared__ alignas(16) u16 lds[65536];   // 131072 B

    // XCD-bijective swizzle (NWG % 8 == 0), n-fastest inside a chunk.
    const int bid = blockIdx.x;
    const int wg  = (bid & 7) * (NWG / 8) + (bid >> 3);
    const long m0 = (long)(wg / NBN) * 256;
    const long n0 = (long)(wg % NBN) * 256;

    const int tid  = threadIdx.x;
    const int wave = tid >> 6, lane = tid & 63;
    const int wm = wave >> 2, wn = wave & 3;

    const u16* Btb = PERBATCH ? (Bt + (m0 >> 12) * (long)(1024 * KDIM)) : Bt;

    // ---- staging addresses (per thread, 2 loads per half-tile) ----
    const int srow = wave * 32 + (lane >> 2);                 // rows srow, srow+16
    const int gch  = ((lane & 3) ^ ((lane >> 3) & 3)) * 8;    // pre-swizzled k-chunk
    const u16* pA0 = A   + (m0 + srow) * KDIM + gch;
    const u16* pA1 = pA0 + 16 * KDIM;
    const u16* pB0 = Btb + (n0 + srow) * KDIM + gch;
    const u16* pB1 = pB0 + 16 * KDIM;

    #define SUB(b_,kh_,ab_) (lds + (((b_)*2+(kh_))*2+(ab_))*8192)
    #define STG_A(b_,kh_,t_) { const int k0_ = (t_)*64 + (kh_)*32;            \
        u16* d_ = SUB(b_,kh_,0) + wave * 1024;                                \
        gload_lds16(pA0 + k0_, d_); gload_lds16(pA1 + k0_, d_ + 512); }
    #define STG_B(b_,kh_,t_) { const int k0_ = (t_)*64 + (kh_)*32;            \
        u16* d_ = SUB(b_,kh_,1) + wave * 1024;                                \
        gload_lds16(pB0 + k0_, d_); gload_lds16(pB1 + k0_, d_ + 512); }

    // ---- fragment read addresses ----
    const int m  = lane & 15, kc = lane >> 4;
    const int off  = (kc ^ ((m >> 1) & 3)) * 8;               // de-swizzle
    const int arow = (wm * 128 + m) * 32 + off;               // + mt*512
    const int brow = (wn * 64  + m) * 32 + off;               // + nh*1024 + j*512

    f32x4  acc[8][4] = {};
    bf16x8 af[8];
    bf16x8 b0, b1;

    #define DSA(b_,kh_) { const u16* s_ = SUB(b_,kh_,0);                      \
        _Pragma("unroll") for (int mt_ = 0; mt_ < 8; ++mt_)                   \
            af[mt_] = *(const bf16x8*)(s_ + arow + mt_ * 512); }
    #define DSB(b_,kh_,nh_) { const u16* s_ = SUB(b_,kh_,1) + brow + (nh_)*1024; \
        b0 = *(const bf16x8*)(s_); b1 = *(const bf16x8*)(s_ + 512); }
    #define MM(nh_) { _Pragma("unroll") for (int mt_ = 0; mt_ < 8; ++mt_) {   \
        acc[mt_][(nh_)*2]   = __builtin_amdgcn_mfma_f32_16x16x32_bf16(        \
            af[mt_], b0, acc[mt_][(nh_)*2],   0, 0, 0);                       \
        acc[mt_][(nh_)*2+1] = __builtin_amdgcn_mfma_f32_16x16x32_bf16(        \
            af[mt_], b1, acc[mt_][(nh_)*2+1], 0, 0, 0); } }
    #define BARMM(nh_)                                                        \
        __builtin_amdgcn_s_barrier();                                         \
        asm volatile("s_waitcnt lgkmcnt(0)" ::: "memory");                    \
        __builtin_amdgcn_s_setprio(1);                                        \
        MM(nh_);                                                              \
        __builtin_amdgcn_s_setprio(0);                                        \
        __builtin_amdgcn_s_barrier();

    // ---- prologue: tile0 (both k-halves) + tile1 k-half0; allow last 4 in flight
    STG_A(0,0,0); STG_B(0,0,0);
    STG_A(0,1,0); STG_B(0,1,0);
    STG_A(1,0,1); STG_B(1,0,1);
    asm volatile("s_waitcnt vmcnt(4)" ::: "memory");
    __builtin_amdgcn_s_barrier();

    // ---- main loop: ITERS iterations x 2 K-tiles (tile 2i in buf0, 2i+1 in buf1)
    #pragma unroll 1
    for (int i = 0; i < ITERS; ++i) {
        const int  t1   = 2 * i + 1;
        const bool more = (i < ITERS - 1);
        // P1 (buf0, kh0, nh0) | stage A kh1(t1) -> buf1
        DSA(0,0); DSB(0,0,0);
        STG_A(1,1,t1);
        BARMM(0);
        // P2 (buf0, kh0, nh1) | stage B kh1(t1)
        DSB(0,0,1);
        STG_B(1,1,t1);
        BARMM(1);
        // P3 (buf0, kh1, nh0) | stage A kh0(t1+1) -> buf0 (kh0 freed at P2)
        DSA(0,1); DSB(0,1,0);
        if (more) STG_A(0,0,t1+1);
        BARMM(0);
        // P4 (buf0, kh1, nh1) | stage B kh0(t1+1); counted wait
        DSB(0,1,1);
        if (more) {
            STG_B(0,0,t1+1);
            asm volatile("s_waitcnt vmcnt(4)" ::: "memory");
        } else {
            asm volatile("s_waitcnt vmcnt(0)" ::: "memory");
        }
        BARMM(1);
        // P5 (buf1, kh0, nh0) | stage A kh1(t1+1) -> buf0 (kh1 freed at P4)
        DSA(1,0); DSB(1,0,0);
        if (more) STG_A(0,1,t1+1);
        BARMM(0);
        // P6 (buf1, kh0, nh1) | stage B kh1(t1+1)
        DSB(1,0,1);
        if (more) STG_B(0,1,t1+1);
        BARMM(1);
        // P7 (buf1, kh1, nh0) | stage A kh0(t1+2) -> buf1 (kh0 freed at P6)
        DSA(1,1); DSB(1,1,0);
        if (more) STG_A(1,0,t1+2);
        BARMM(0);
        // P8 (buf1, kh1, nh1) | stage B kh0(t1+2); counted wait
        DSB(1,1,1);
        if (more) {
            STG_B(1,0,t1+2);
            asm volatile("s_waitcnt vmcnt(4)" ::: "memory");
        }
        BARMM(1);
    }

    // ---- epilogue via LDS: coalesced 16B stores, no write amplification ----
    if constexpr (sizeof(OutT) == 2) {
        const bool dorelu = RELUQK && (n0 < 1024);
        #pragma unroll
        for (int nf = 0; nf < 4; ++nf) {
            const int col = wn * 64 + nf * 16 + m;
            const float bval = bias[n0 + col];
            #pragma unroll
            for (int mt = 0; mt < 8; ++mt) {
                #pragma unroll
                for (int r = 0; r < 4; ++r) {
                    const int row = wm * 128 + mt * 16 + kc * 4 + r;
                    float c = acc[mt][nf][r] + bval;
                    if (dorelu) c = fmaxf(c, 0.f) * 0.17677669529663687f;  // 1/sqrt(32)
                    const int x = ((row >> 2) & 7) << 1;
                    lds[row * 256 + (((col >> 3) ^ x) << 3) + (col & 7)] = f2bf(c);
                }
            }
        }
        __syncthreads();
        #pragma unroll
        for (int it = 0; it < 16; ++it) {
            const int li = it * 512 + tid;
            const int row = li >> 5, ch = li & 31;
            const int x = ((row >> 2) & 7) << 1;
            bf16x8 v = *(const bf16x8*)&lds[row * 256 + ((ch ^ x) << 3)];
            *(bf16x8*)&C[(m0 + row) * (long)NCOLS + n0 + ch * 8] = v;
        }
    } else {
        float* ft = (float*)lds;                 // 128 rows x 256 f32 = 128 KiB/half
        #pragma unroll 1
        for (int half = 0; half < 2; ++half) {
            __syncthreads();
            if (wm == half) {
                #pragma unroll
                for (int nf = 0; nf < 4; ++nf) {
                    const int col = wn * 64 + nf * 16 + m;
                    const float bval = bias[n0 + col];
                    #pragma unroll
                    for (int mt = 0; mt < 8; ++mt) {
                        #pragma unroll
                        for (int r = 0; r < 4; ++r) {
                            const int row = mt * 16 + kc * 4 + r;   // 0..127
                            const int x = ((row >> 2) & 7) << 1;
                            ft[row * 256 + (((col >> 2) ^ x) << 2) + (col & 3)] =
                                acc[mt][nf][r] + bval;
                        }
                    }
                }
            }
            __syncthreads();
            #pragma unroll
            for (int it = 0; it < 16; ++it) {
                const int li = it * 512 + tid;
                const int row = li >> 6, ch = li & 63;
                const int x = ((row >> 2) & 7) << 1;
                float4 v = *(const float4*)&ft[row * 256 + ((ch ^ x) << 2)];
                *(float4*)&C[(m0 + half * 128 + row) * (long)NCOLS + n0 + ch * 4] = v;
            }
        }
    }
    #undef SUB
    #undef STG_A
    #undef STG_B
    #undef DSA
    #undef DSB
    #undef MM
    #undef BARMM
}

// ---------------------------------------------------------------- kv v4: 128-row chunks, f32 LDS tiles (no per-fma cvt)
// grid (bh=64, chunk=32). part_kv[bh][chunk][f][d], part_ks[bh][chunk][f].
__global__ __launch_bounds__(256) void kv_v3(const u16* __restrict__ Y,
                                             float* __restrict__ part_kv,
                                             float* __restrict__ part_ks)
{
    __shared__ float ksf[128 * 33];   // [n][f] f32, pad 33
    __shared__ float vsf[128 * 68];   // [n][d] f32, pad 68 (16B-aligned rows)
    const int bh = blockIdx.x, c = blockIdx.y;
    const int b = bh >> 4, h = bh & 15;
    const int tid = threadIdx.x;
    const long rbase = (long)b * 4096 + (long)c * 128;

    #pragma unroll
    for (int it = 0; it < 2; ++it) {
        const int lr = it * 64 + (tid >> 2), cc = (tid & 3) * 8;
        bf16x8 kx = *(const bf16x8*)(Y + (rbase + lr) * 2048 + 512 + h * 32 + cc);
        #pragma unroll
        for (int j = 0; j < 8; ++j) ksf[lr * 33 + cc + j] = bf2f((u16)kx[j]);
    }
    #pragma unroll
    for (int it = 0; it < 4; ++it) {
        const int lr = it * 32 + (tid >> 3), cc = (tid & 7) * 8;
        bf16x8 vx = *(const bf16x8*)(Y + (rbase + lr) * 2048 + 1024 + h * 64 + cc);
        #pragma unroll
        for (int j = 0; j < 8; ++j) vsf[lr * 68 + cc + j] = bf2f((u16)vx[j]);
    }
    __syncthreads();

    const int f = tid >> 3, dg = (tid & 7) * 8;
    float acc[8] = {};
    float ksacc = 0.f;
    #pragma unroll 4
    for (int n = 0; n < 128; ++n) {
        const float kf = ksf[n * 33 + f];
        const float4 v0 = *(const float4*)&vsf[n * 68 + dg];
        const float4 v1 = *(const float4*)&vsf[n * 68 + dg + 4];
        acc[0] += kf * v0.x; acc[1] += kf * v0.y;
        acc[2] += kf * v0.z; acc[3] += kf * v0.w;
        acc[4] += kf * v1.x; acc[5] += kf * v1.y;
        acc[6] += kf * v1.z; acc[7] += kf * v1.w;
        ksacc += kf;
    }

    float* o = part_kv + (((long)bh * 32 + c) * 32 + f) * 64 + dg;
    *(f32x4*)o       = f32x4{acc[0], acc[1], acc[2], acc[3]};
    *(f32x4*)(o + 4) = f32x4{acc[4], acc[5], acc[6], acc[7]};
    if ((tid & 7) == 0) part_ks[(bh * 32 + c) * 32 + f] = ksacc;
}

// reduce 32 partials -> kv[bh][f][d] (blocks 0..511) and ksum[bh][f] (512..519)
__global__ __launch_bounds__(256) void kv_reduce(const float* __restrict__ part_kv,
                                                 const float* __restrict__ part_ks,
                                                 float* __restrict__ kv,
                                                 float* __restrict__ ksum)
{
    const int idx = blockIdx.x * 256 + threadIdx.x;
    if (blockIdx.x < 512) {                       // 131072 kv elements
        const int bh = idx >> 11, off = idx & 2047;
        const float* p = part_kv + (long)bh * 65536 + off;
        float s = 0.f;
        #pragma unroll 8
        for (int c = 0; c < 32; c++) s += p[c * 2048];
        kv[idx] = s;
    } else {                                      // 2048 ksum elements
        const int i2 = idx - 512 * 256;
        const int bh = i2 >> 5, f = i2 & 31;
        const float* p = part_ks + bh * 1024 + f;
        float s = 0.f;
        #pragma unroll 8
        for (int c = 0; c < 32; c++) s += p[c * 32];
        ksum[i2] = s;
    }
}

// ---------------------------------------------------------------- gmat: GT[b][n][h*32+f] = (kv_bh @ Wo_h)^T, bf16
// grid 256: bid = bh*4 + ntile. LDS: kv (8 KB) + Wo panel 64x256 (64 KB).
__global__ __launch_bounds__(256) void gmat(const float* __restrict__ kv,
                                            const float* __restrict__ Wo,
                                            u16* __restrict__ GT)
{
    __shared__ float kvl[2048];
    __shared__ float wol[64 * 256];
    const int bid = blockIdx.x, tid = threadIdx.x;
    const int bh = bid >> 2, n0 = (bid & 3) * 256;
    const int b = bh >> 4, h = bh & 15;

    {
        const float4* s = (const float4*)(kv + (long)bh * 2048);
        float4* d = (float4*)kvl;
        d[tid] = s[tid];
        d[256 + tid] = s[256 + tid];
    }
    #pragma unroll
    for (int it = 0; it < 16; ++it) {
        const int li = it * 256 + tid;
        const int row = li >> 6, c4 = (li & 63) * 4;
        *(float4*)&wol[row * 256 + c4] =
            *(const float4*)&Wo[(long)(h * 64 + row) * 1024 + n0 + c4];
    }
    __syncthreads();

    float out[32] = {};
    #pragma unroll
    for (int d4 = 0; d4 < 16; ++d4) {
        const float w0 = wol[(d4 * 4 + 0) * 256 + tid];
        const float w1 = wol[(d4 * 4 + 1) * 256 + tid];
        const float w2 = wol[(d4 * 4 + 2) * 256 + tid];
        const float w3 = wol[(d4 * 4 + 3) * 256 + tid];
        #pragma unroll
        for (int f = 0; f < 32; ++f) {
            const float4 kq = *(const float4*)&kvl[f * 64 + d4 * 4];
            out[f] += kq.x * w0 + kq.y * w1 + kq.z * w2 + kq.w * w3;
        }
    }

    u16* dst = GT + ((long)b * 1024 + n0 + tid) * 512 + h * 32;
    #pragma unroll
    for (int q8 = 0; q8 < 4; ++q8) {
        bf16x8 o;
        #pragma unroll
        for (int j = 0; j < 8; ++j) o[j] = (short)f2bf(out[q8 * 8 + j]);
        *(bf16x8*)&dst[q8 * 8] = o;
    }
}

// ---------------------------------------------------------------- zq: zq[r][h*32+f] = q'[r][f] / (q'[r]*ksum + eps), bf16
// grid (bh=64, chunk=64). Reuses attn_v2's verified staging + den structure.
__global__ __launch_bounds__(256) void zq_k(const u16* __restrict__ Y,
                                            const float* __restrict__ ksum,
                                            u16* __restrict__ zq)
{
    __shared__ float qsf[64 * 36];    // [row][f] f32, pad 36
    __shared__ float kss[32];
    __shared__ float zs[64];
    const int tid = threadIdx.x;
    const int bh = blockIdx.x;
    const int b = bh >> 4, h = bh & 15;
    const long row0 = (long)b * 4096 + (long)blockIdx.y * 64;

    const int lr = tid >> 2, c8 = (tid & 3) * 8;
    {
        bf16x8 qx = *(const bf16x8*)(Y + (row0 + lr) * 2048 + h * 32 + c8);
        #pragma unroll
        for (int j = 0; j < 8; ++j) qsf[lr * 36 + c8 + j] = bf2f((u16)qx[j]);
    }
    if (tid < 32) kss[tid] = ksum[bh * 32 + tid];
    __syncthreads();

    {
        const int wave = tid >> 6, lane = tid & 63;
        const int r = wave * 16 + (lane & 15);
        float den = 0.f;
        #pragma unroll
        for (int fc = 0; fc < 8; ++fc) {
            const float4 q = *(const float4*)&qsf[r * 36 + fc * 4];
            den += q.x * kss[fc * 4]     + q.y * kss[fc * 4 + 1]
                 + q.z * kss[fc * 4 + 2] + q.w * kss[fc * 4 + 3];
        }
        if (lane < 16) zs[r] = 1.f / (den + 1e-8f);
    }
    __syncthreads();

    const float z = zs[lr];
    bf16x8 o;
    #pragma unroll
    for (int j = 0; j < 8; ++j) o[j] = (short)f2bf(qsf[lr * 36 + c8 + j] * z);
    *(bf16x8*)&zq[(row0 + lr) * 512 + h * 32 + c8] = o;
}

// ---------------------------------------------------------------- launch
extern "C" void kernel_launch(void* const* d_in, const int* in_sizes, int n_in,
                              void* d_out, int out_size, void* d_ws, size_t ws_size,
                              hipStream_t stream)
{
    const float* x    = (const float*)d_in[0];
    const float* Wq   = (const float*)d_in[1];
    const float* bq   = (const float*)d_in[2];
    const float* Wk   = (const float*)d_in[3];
    const float* bk   = (const float*)d_in[4];
    const float* Wv   = (const float*)d_in[5];
    const float* bv   = (const float*)d_in[6];
    const float* proj = (const float*)d_in[7];
    const float* Wo   = (const float*)d_in[8];
    const float* bo   = (const float*)d_in[9];

    // Region w+0 (33.5 MB) time-multiplexed: xbf (dies at gemm_qkv) ->
    // part_kv [kv_v3..kv_reduce, 16.8 MB at w+0] -> zqb [zq_k..gemm_out, 16.8 MB
    // at w+0] + GT [gmat..gemm_out, 4.2 MB at w+16M].
    char* w = (char*)d_ws;
    u16*   xbf     = (u16*)  (w);                  // 33,554,432 B
    float* part_kv = (float*)(w);                  // alias (16,777,216 B used)
    u16*   zqb     = (u16*)  (w);                  // alias (16,777,216 B used)
    u16*   GT      = (u16*)  (w + 16777216);       //  4,194,304 B (alias, after kv_reduce)
    u16*   wallT   = (u16*)  (w + 33554432);       //  4,194,304 B
    float* bias    = (float*)(w + 39845888);       //      8,192 B
    float* kv      = (float*)(w + 39854080);       //    524,288 B
    float* ksum    = (float*)(w + 40378368);       //      8,192 B
    u16*   Y       = (u16*)  (w + 40386560);       // 67,108,864 B
    float* part_ks = (float*)(w + 107495424);      //    262,144 B used

    prep<<<8704, 256, 0, stream>>>((const float4*)x, (bf16x8*)xbf,
                                   Wq, Wk, bq, bk, proj, Wv, bv,
                                   wallT, bias);

    gemm256<8, true, u16, 1024, false><<<512, 512, 0, stream>>>(xbf, wallT, bias, Y);

    kv_v3<<<dim3(64, 32), 256, 0, stream>>>(Y, part_kv, part_ks);

    kv_reduce<<<520, 256, 0, stream>>>(part_kv, part_ks, kv, ksum);

    gmat<<<256, 256, 0, stream>>>(kv, Wo, GT);

    zq_k<<<dim3(64, 64), 256, 0, stream>>>(Y, ksum, zqb);

    gemm256<4, false, float, 512, true><<<256, 512, 0, stream>>>(zqb, GT, bo, (float*)d_out);
}